// Round 5
// baseline (141.315 us; speedup 1.0000x reference)
//
#include <hip/hip_runtime.h>
#include <math.h>

#define D  256
#define T  768
#define N  384
#define FD 512

#define DOT4(A,B) ((A).x*(B).x + (A).y*(B).y + (A).z*(B).z + (A).w*(B).w)

// ---------- node 1: k_front ------------------------------------------------------
// blocks [0,192)   : conv1d as tile-GEMM (32t x 32o tiles, K=768 = 3k x 256i)
// blocks [192,288) : text row-l2-normalize (4 rows/block, wave per row)
// blocks [288,292) : ut/uv = Wi.T @ wt/wv  (split in f-halves)
__global__ __launch_bounds__(256) void k_front(
    const float* __restrict__ vf, const float* __restrict__ vpos,
    const float* __restrict__ cw, const float* __restrict__ cb,
    const float* __restrict__ tf, const float* __restrict__ tpos,
    const float* __restrict__ Wi, const float* __restrict__ wt,
    const float* __restrict__ wv,
    float* __restrict__ ve, float* __restrict__ tn,
    float* __restrict__ ut, float* __restrict__ uv)
{
    __shared__ float As[32][68];
    __shared__ float Bs[32][68];
    const int b = blockIdx.x, tid = threadIdx.x;

    if (b < 192) {
        const int t0 = (b >> 3) * 32;          // 24 t-tiles
        const int o0 = (b & 7) * 32;           // 8 o-tiles
        const int tA = tid >> 4, oA = tid & 15;
        float acc00 = 0.f, acc01 = 0.f, acc10 = 0.f, acc11 = 0.f;

        for (int c = 0; c < 12; ++c) {
            const int k = c >> 2, i0 = (c & 3) << 6;
            __syncthreads();
            {
                const int kc = tid & 63;
                const int g = tid >> 6;
#pragma unroll
                for (int it = 0; it < 8; ++it) {
                    int tt = g + it*4;
                    int tg_ = t0 + tt + k - 1;
                    float v = 0.f;
                    if (tg_ >= 0 && tg_ < T)
                        v = vf[tg_*D + i0 + kc] + vpos[tg_*D + i0 + kc];
                    As[tt][kc] = v;
                }
#pragma unroll
                for (int ib = 0; ib < 8; ++ib) {
                    int oc = g + ib*4;
                    Bs[oc][kc] = cw[(o0 + oc)*768 + (i0 + kc)*3 + k];
                }
            }
            __syncthreads();
#pragma unroll
            for (int kc4 = 0; kc4 < 16; ++kc4) {
                float4 a0 = *(const float4*)&As[tA][kc4*4];
                float4 a1 = *(const float4*)&As[tA+16][kc4*4];
                float4 b0 = *(const float4*)&Bs[oA][kc4*4];
                float4 b1 = *(const float4*)&Bs[oA+16][kc4*4];
                acc00 += DOT4(a0, b0); acc01 += DOT4(a0, b1);
                acc10 += DOT4(a1, b0); acc11 += DOT4(a1, b1);
            }
        }
        const float bia = cb[o0 + oA], bib = cb[o0 + oA + 16];
        ve[(t0 + tA)*D + o0 + oA]           = fmaxf(acc00 + bia, 0.f);
        ve[(t0 + tA)*D + o0 + oA + 16]      = fmaxf(acc01 + bib, 0.f);
        ve[(t0 + tA + 16)*D + o0 + oA]      = fmaxf(acc10 + bia, 0.f);
        ve[(t0 + tA + 16)*D + o0 + oA + 16] = fmaxf(acc11 + bib, 0.f);
    } else if (b < 288) {
        const int wid = tid >> 6, lane = tid & 63;
        const int r = (b - 192)*4 + wid;
        float v[4]; float ss = 0.f;
#pragma unroll
        for (int kk = 0; kk < 4; ++kk) {
            v[kk] = tf[r*D + lane + 64*kk] + tpos[r*D + lane + 64*kk];
            ss += v[kk]*v[kk];
        }
#pragma unroll
        for (int off = 1; off < 64; off <<= 1) ss += __shfl_xor(ss, off);
        float inv = 1.0f / fmaxf(sqrtf(ss), 1e-12f);
#pragma unroll
        for (int kk = 0; kk < 4; ++kk) tn[r*D + lane + 64*kk] = v[kk] * inv;
    } else {
        float* wsm = &As[0][0];
        const int which = b - 288;                  // 0,1 -> ut ; 2,3 -> uv
        const float* w = (which < 2) ? wt : wv;
        float* u = (which < 2) ? ut : uv;
        const int f = ((which & 1) << 8) + tid;
        wsm[tid] = w[tid];
        __syncthreads();
        float s = 0.f;
#pragma unroll 4
        for (int d = 0; d < D; ++d) s += wsm[d] * Wi[d*FD + f];
        u[f] = s;
    }
}

// ---------- node 2: k_mid --------------------------------------------------------
// blocks [0,384)   : f1 = ve @ W1.T + b1 as tile-GEMM (32t x 32f, K=256)
// blocks [384,392) : q = (mean_rows tn) @ bil_w (32 outputs/block)
__global__ __launch_bounds__(256) void k_mid(
    const float* __restrict__ ve, const float* __restrict__ W1,
    const float* __restrict__ b1, const float* __restrict__ tn,
    const float* __restrict__ bil,
    float* __restrict__ f1, float* __restrict__ q)
{
    __shared__ float As[32][68];
    __shared__ float Bs[32][68];
    const int b = blockIdx.x, tid = threadIdx.x;

    if (b < 384) {
        const int t0 = (b >> 4) * 32;          // 24 t-tiles
        const int f0 = (b & 15) * 32;          // 16 f-tiles
        const int tA = tid >> 4, fA = tid & 15;
        float acc00 = 0.f, acc01 = 0.f, acc10 = 0.f, acc11 = 0.f;

        for (int c = 0; c < 4; ++c) {
            const int d0 = c << 6;
            __syncthreads();
            {
                const int kc = tid & 63;
                const int g = tid >> 6;
#pragma unroll
                for (int it = 0; it < 8; ++it) {
                    int tt = g + it*4;
                    As[tt][kc] = ve[(t0 + tt)*D + d0 + kc];
                    Bs[tt][kc] = W1[(f0 + tt)*D + d0 + kc];
                }
            }
            __syncthreads();
#pragma unroll
            for (int kc4 = 0; kc4 < 16; ++kc4) {
                float4 a0 = *(const float4*)&As[tA][kc4*4];
                float4 a1 = *(const float4*)&As[tA+16][kc4*4];
                float4 b0 = *(const float4*)&Bs[fA][kc4*4];
                float4 b1 = *(const float4*)&Bs[fA+16][kc4*4];
                acc00 += DOT4(a0, b0); acc01 += DOT4(a0, b1);
                acc10 += DOT4(a1, b0); acc11 += DOT4(a1, b1);
            }
        }
        const float bia = b1[f0 + fA], bib = b1[f0 + fA + 16];
        f1[(t0 + tA)*FD + f0 + fA]           = acc00 + bia;
        f1[(t0 + tA)*FD + f0 + fA + 16]      = acc01 + bib;
        f1[(t0 + tA + 16)*FD + f0 + fA]      = acc10 + bia;
        f1[(t0 + tA + 16)*FD + f0 + fA + 16] = acc11 + bib;
    } else {
        __shared__ float tb[D];
        __shared__ float qp[8][32];
        const int bq = b - 384;                 // 0..7, outputs q[bq*32 .. +32)
        float s = 0.f;
#pragma unroll 8
        for (int n = 0; n < N; ++n) s += tn[n*D + tid];
        tb[tid] = s * (1.0f / (float)N);
        __syncthreads();
        const int o = tid & 31, dg = tid >> 5;
        float p = 0.f;
#pragma unroll 8
        for (int d = dg*32; d < dg*32 + 32; ++d) p += tb[d] * bil[d*D + bq*32 + o];
        qp[dg][o] = p;
        __syncthreads();
        if (tid < 32) {
            float acc = 0.f;
#pragma unroll
            for (int kk = 0; kk < 8; ++kk) acc += qp[kk][tid];
            q[bq*32 + tid] = acc;
        }
    }
}

// ---------- node 3: k_gnn (2 rows/block, 192 blocks) ------------------------------
__global__ __launch_bounds__(256) void k_gnn(
    const float* __restrict__ tn_, const float* __restrict__ q,
    const float* __restrict__ lin_w, const float* __restrict__ lin_b,
    const float* __restrict__ W2,
    float* __restrict__ tg, float* __restrict__ f2)
{
    __shared__ float tns[2][D];
    __shared__ float tgs[2][D];
    __shared__ float qs[D];
    __shared__ float pp[4];
    __shared__ float wgt[2];
    const int tid = threadIdx.x;
    const int n0 = blockIdx.x * 2;
    qs[tid] = q[tid];
    tns[0][tid] = tn_[n0*D + tid];
    tns[1][tid] = tn_[(n0 + 1)*D + tid];
    __syncthreads();

    const int wid = tid >> 6, lane = tid & 63;
    {
        const int r = wid & 1, base = (wid >> 1) * 128;
        float p = tns[r][base + lane] * qs[base + lane]
                + tns[r][base + lane + 64] * qs[base + lane + 64];
#pragma unroll
        for (int off = 32; off; off >>= 1) p += __shfl_down(p, off);
        if (lane == 0) pp[wid] = p;
    }
    __syncthreads();
    if (tid < 2) wgt[tid] = 1.0f / (1.0f + expf(-(pp[tid] + pp[tid + 2])));
    __syncthreads();

    float accl[2] = {0.f, 0.f};
    const float* lwr = lin_w + tid * D;
    for (int d0 = 0; d0 < D; d0 += 4) {
        float4 w4 = *(const float4*)(lwr + d0);
#pragma unroll
        for (int r = 0; r < 2; ++r) {
            float4 tv = *(const float4*)&tns[r][d0];
            accl[r] += DOT4(w4, tv);
        }
    }
    float lb = lin_b[tid];
#pragma unroll
    for (int r = 0; r < 2; ++r) {
        float gg = wgt[r] * (accl[r] + lb);
        tgs[r][tid] = gg;
        tg[(n0 + r)*D + tid] = gg;
    }
    __syncthreads();

    float c0[2] = {0.f, 0.f}, c1[2] = {0.f, 0.f};
    const float* w2r0 = W2 + tid * D;
    const float* w2r1 = W2 + (tid + 256) * D;
    for (int d0 = 0; d0 < D; d0 += 4) {
        float4 wa = *(const float4*)(w2r0 + d0);
        float4 wb = *(const float4*)(w2r1 + d0);
#pragma unroll
        for (int r = 0; r < 2; ++r) {
            float4 tv = *(const float4*)&tgs[r][d0];
            c0[r] += DOT4(wa, tv);
            c1[r] += DOT4(wb, tv);
        }
    }
#pragma unroll
    for (int r = 0; r < 2; ++r) {
        f2[(n0 + r)*FD + tid]       = c0[r];
        f2[(n0 + r)*FD + tid + 256] = c1[r];
    }
}

// ---------- node 4: k_score  (FD split over blockIdx.z, partial outputs) ----------
__global__ __launch_bounds__(256) void k_score(
    const float* __restrict__ f1, const float* __restrict__ f2,
    const float* __restrict__ ut, const float* __restrict__ uv,
    float* __restrict__ stp, float* __restrict__ svp)
{
    __shared__ float f1s[32][132];
    __shared__ float f2s[32][132];
    __shared__ float us_t[128];
    __shared__ float us_v[128];
    const int tid = threadIdx.x;
    const int t0 = blockIdx.x * 32, n0 = blockIdx.y * 32, c = blockIdx.z;

    if (tid < 128) { us_t[tid] = ut[c*128 + tid]; us_v[tid] = uv[c*128 + tid]; }
    for (int j = tid; j < 1024; j += 256) {
        int r = j >> 5, c4 = (j & 31) * 4;
        *(float4*)&f1s[r][c4] = *(const float4*)&f1[(t0 + r)*FD + c*128 + c4];
        *(float4*)&f2s[r][c4] = *(const float4*)&f2[(n0 + r)*FD + c*128 + c4];
    }
    __syncthreads();

    const int tA = 2 * (tid >> 4);
    const int nA = tid & 15;

    float at00=0.f, at01=0.f, at10=0.f, at11=0.f;
    float av00=0.f, av01=0.f, av10=0.f, av11=0.f;

#pragma unroll 8
    for (int fq = 0; fq < 32; ++fq) {
        float4 u_t = *(const float4*)&us_t[fq*4];
        float4 u_v = *(const float4*)&us_v[fq*4];
        float4 a0 = *(const float4*)&f1s[tA][fq*4];
        float4 a1 = *(const float4*)&f1s[tA+1][fq*4];
        float4 b0 = *(const float4*)&f2s[nA][fq*4];
        float4 b1 = *(const float4*)&f2s[nA+16][fq*4];
#pragma unroll
        for (int e = 0; e < 4; ++e) {
            float ue_t = ((const float*)&u_t)[e];
            float ue_v = ((const float*)&u_v)[e];
            float a0e = ((const float*)&a0)[e], a1e = ((const float*)&a1)[e];
            float b0e = ((const float*)&b0)[e], b1e = ((const float*)&b1)[e];
            float h00 = fmaxf(a0e + b0e, 0.f);
            float h01 = fmaxf(a0e + b1e, 0.f);
            float h10 = fmaxf(a1e + b0e, 0.f);
            float h11 = fmaxf(a1e + b1e, 0.f);
            at00 += h00*ue_t; av00 += h00*ue_v;
            at01 += h01*ue_t; av01 += h01*ue_v;
            at10 += h10*ue_t; av10 += h10*ue_v;
            at11 += h11*ue_t; av11 += h11*ue_v;
        }
    }
    const int t = t0 + tA, n = n0 + nA;
    float* stz = stp + c * (T*N);
    float* svz = svp + c * (N*T);
    stz[t*N + n]        = at00;  stz[t*N + n + 16]     = at01;
    stz[(t+1)*N + n]    = at10;  stz[(t+1)*N + n + 16] = at11;
    *(float2*)&svz[n*T + t]      = make_float2(av00, av10);
    *(float2*)&svz[(n+16)*T + t] = make_float2(av01, av11);
}

// ---------- node 5: k_att  (combine partials + softmax + context + epilogue) ------
__global__ __launch_bounds__(256) void k_att(
    const float* __restrict__ stp, const float* __restrict__ svp,
    const float* __restrict__ tg, const float* __restrict__ ve,
    const float* __restrict__ vf, const float* __restrict__ tf,
    float* __restrict__ out_v, float* __restrict__ out_t)
{
    __shared__ float attb[768][8];
    __shared__ float red[4][8];
    __shared__ float ptA[4][8][64];
    __shared__ float ptB[4][8][64];
    const int tid = threadIdx.x;
    const int oo = tid & 63, g = tid >> 6;

    if (blockIdx.x < 192) {
        const int bx = blockIdx.x >> 1, h = blockIdx.x & 1;
        const int t0 = bx * 8;
        const int oA = h*128 + oo, oB = oA + 64;

        float v1[8], v2[8];
#pragma unroll
        for (int r = 0; r < 8; ++r) {
            const float* p = stp + (t0 + r)*N + tid;
            v1[r] = p[0] + p[T*N] + p[2*T*N] + p[3*T*N];
            if (tid < 128) {
                const float* p2 = p + 256;
                v2[r] = p2[0] + p2[T*N] + p2[2*T*N] + p2[3*T*N];
            } else v2[r] = -1e30f;
        }
        float m[8], si[8];
#pragma unroll
        for (int r = 0; r < 8; ++r) {
            float mm = fmaxf(v1[r], v2[r]);
#pragma unroll
            for (int off = 1; off < 64; off <<= 1) mm = fmaxf(mm, __shfl_xor(mm, off));
            if (oo == 0) red[g][r] = mm;
        }
        __syncthreads();
#pragma unroll
        for (int r = 0; r < 8; ++r)
            m[r] = fmaxf(fmaxf(red[0][r], red[1][r]), fmaxf(red[2][r], red[3][r]));
        __syncthreads();
        float e1[8], e2[8];
#pragma unroll
        for (int r = 0; r < 8; ++r) {
            e1[r] = expf(v1[r] - m[r]);
            e2[r] = (tid < 128) ? expf(v2[r] - m[r]) : 0.f;
            float ss = e1[r] + e2[r];
#pragma unroll
            for (int off = 1; off < 64; off <<= 1) ss += __shfl_xor(ss, off);
            if (oo == 0) red[g][r] = ss;
        }
        __syncthreads();
#pragma unroll
        for (int r = 0; r < 8; ++r)
            si[r] = 1.0f / (red[0][r] + red[1][r] + red[2][r] + red[3][r]);
#pragma unroll
        for (int r = 0; r < 8; ++r) {
            attb[tid][r] = e1[r] * si[r];
            if (tid < 128) attb[tid + 256][r] = e2[r] * si[r];
        }
        __syncthreads();

        float accA[8] = {0.f,0.f,0.f,0.f,0.f,0.f,0.f,0.f};
        float accB[8] = {0.f,0.f,0.f,0.f,0.f,0.f,0.f,0.f};
#pragma unroll 4
        for (int n = g; n < N; n += 4) {
            float4 a0 = *(const float4*)&attb[n][0];
            float4 a1 = *(const float4*)&attb[n][4];
            float tvA = tg[n*D + oA], tvB = tg[n*D + oB];
            accA[0] += a0.x*tvA; accA[1] += a0.y*tvA; accA[2] += a0.z*tvA; accA[3] += a0.w*tvA;
            accA[4] += a1.x*tvA; accA[5] += a1.y*tvA; accA[6] += a1.z*tvA; accA[7] += a1.w*tvA;
            accB[0] += a0.x*tvB; accB[1] += a0.y*tvB; accB[2] += a0.z*tvB; accB[3] += a0.w*tvB;
            accB[4] += a1.x*tvB; accB[5] += a1.y*tvB; accB[6] += a1.z*tvB; accB[7] += a1.w*tvB;
        }
#pragma unroll
        for (int r = 0; r < 8; ++r) { ptA[g][r][oo] = accA[r]; ptB[g][r][oo] = accB[r]; }
        __syncthreads();
#pragma unroll
        for (int rr = g; rr < 8; rr += 4) {
            float sA = ptA[0][rr][oo] + ptA[1][rr][oo] + ptA[2][rr][oo] + ptA[3][rr][oo];
            float sB = ptB[0][rr][oo] + ptB[1][rr][oo] + ptB[2][rr][oo] + ptB[3][rr][oo];
            int t = t0 + rr;
            out_v[t*D + oA] = 0.5f*sA + 0.5f*ve[t*D + oA] + vf[t*D + oA];
            out_v[t*D + oB] = 0.5f*sB + 0.5f*ve[t*D + oB] + vf[t*D + oB];
        }
    } else {
        const int b2 = blockIdx.x - 192;
        const int bx = b2 >> 1, h = b2 & 1;
        const int n0 = bx * 8;
        const int oA = h*128 + oo, oB = oA + 64;

        float v1[8], v2[8], v3[8];
#pragma unroll
        for (int r = 0; r < 8; ++r) {
            const float* p = svp + (n0 + r)*T + tid;
            v1[r] = p[0]   + p[N*T]       + p[2*N*T]       + p[3*N*T];
            v2[r] = p[256] + p[N*T + 256] + p[2*N*T + 256] + p[3*N*T + 256];
            v3[r] = p[512] + p[N*T + 512] + p[2*N*T + 512] + p[3*N*T + 512];
        }
        float m[8], si[8];
#pragma unroll
        for (int r = 0; r < 8; ++r) {
            float mm = fmaxf(fmaxf(v1[r], v2[r]), v3[r]);
#pragma unroll
            for (int off = 1; off < 64; off <<= 1) mm = fmaxf(mm, __shfl_xor(mm, off));
            if (oo == 0) red[g][r] = mm;
        }
        __syncthreads();
#pragma unroll
        for (int r = 0; r < 8; ++r)
            m[r] = fmaxf(fmaxf(red[0][r], red[1][r]), fmaxf(red[2][r], red[3][r]));
        __syncthreads();
        float e1[8], e2[8], e3[8];
#pragma unroll
        for (int r = 0; r < 8; ++r) {
            e1[r] = expf(v1[r] - m[r]);
            e2[r] = expf(v2[r] - m[r]);
            e3[r] = expf(v3[r] - m[r]);
            float ss = e1[r] + e2[r] + e3[r];
#pragma unroll
            for (int off = 1; off < 64; off <<= 1) ss += __shfl_xor(ss, off);
            if (oo == 0) red[g][r] = ss;
        }
        __syncthreads();
#pragma unroll
        for (int r = 0; r < 8; ++r)
            si[r] = 1.0f / (red[0][r] + red[1][r] + red[2][r] + red[3][r]);
#pragma unroll
        for (int r = 0; r < 8; ++r) {
            attb[tid][r]       = e1[r] * si[r];
            attb[tid + 256][r] = e2[r] * si[r];
            attb[tid + 512][r] = e3[r] * si[r];
        }
        __syncthreads();

        float accA[8] = {0.f,0.f,0.f,0.f,0.f,0.f,0.f,0.f};
        float accB[8] = {0.f,0.f,0.f,0.f,0.f,0.f,0.f,0.f};
#pragma unroll 4
        for (int t = g; t < T; t += 4) {
            float4 a0 = *(const float4*)&attb[t][0];
            float4 a1 = *(const float4*)&attb[t][4];
            float vvA = ve[t*D + oA], vvB = ve[t*D + oB];
            accA[0] += a0.x*vvA; accA[1] += a0.y*vvA; accA[2] += a0.z*vvA; accA[3] += a0.w*vvA;
            accA[4] += a1.x*vvA; accA[5] += a1.y*vvA; accA[6] += a1.z*vvA; accA[7] += a1.w*vvA;
            accB[0] += a0.x*vvB; accB[1] += a0.y*vvB; accB[2] += a0.z*vvB; accB[3] += a0.w*vvB;
            accB[4] += a1.x*vvB; accB[5] += a1.y*vvB; accB[6] += a1.z*vvB; accB[7] += a1.w*vvB;
        }
#pragma unroll
        for (int r = 0; r < 8; ++r) { ptA[g][r][oo] = accA[r]; ptB[g][r][oo] = accB[r]; }
        __syncthreads();
#pragma unroll
        for (int rr = g; rr < 8; rr += 4) {
            float sA = ptA[0][rr][oo] + ptA[1][rr][oo] + ptA[2][rr][oo] + ptA[3][rr][oo];
            float sB = ptB[0][rr][oo] + ptB[1][rr][oo] + ptB[2][rr][oo] + ptB[3][rr][oo];
            int n = n0 + rr;
            out_t[n*D + oA] = 0.5f*sA + 0.5f*tg[n*D + oA] + tf[n*D + oA];
            out_t[n*D + oB] = 0.5f*sB + 0.5f*tg[n*D + oB] + tf[n*D + oB];
        }
    }
}

extern "C" void kernel_launch(void* const* d_in, const int* in_sizes, int n_in,
                              void* d_out, int out_size, void* d_ws, size_t ws_size,
                              hipStream_t stream)
{
    (void)in_sizes; (void)n_in; (void)out_size; (void)ws_size;
    const float* vf   = (const float*)d_in[0];
    const float* tf   = (const float*)d_in[1];
    const float* vpos = (const float*)d_in[2];
    const float* tpos = (const float*)d_in[3];
    const float* cw   = (const float*)d_in[4];
    const float* cb   = (const float*)d_in[5];
    const float* bil  = (const float*)d_in[6];
    const float* lw   = (const float*)d_in[7];
    const float* lb   = (const float*)d_in[8];
    const float* W1   = (const float*)d_in[9];
    const float* b1   = (const float*)d_in[10];
    const float* W2   = (const float*)d_in[11];
    const float* Wi   = (const float*)d_in[12];
    // d_in[13]=bi, d_in[15]=bt, d_in[17]=bv: softmax-invariant constant shifts -> unused
    const float* wt   = (const float*)d_in[14];
    const float* wv   = (const float*)d_in[16];

    float* ws  = (float*)d_ws;
    float* ve  = ws;                // T*D
    float* tn  = ve + T*D;          // N*D
    float* tg  = tn + N*D;          // N*D
    float* f1  = tg + N*D;          // T*FD
    float* f2  = f1 + T*FD;         // N*FD
    float* q   = f2 + N*FD;         // D
    float* ut  = q + D;             // FD
    float* uv  = ut + FD;           // FD
    float* stp = uv + FD;           // 4*T*N
    float* svp = stp + 4*T*N;       // 4*N*T

    float* out_v = (float*)d_out;
    float* out_t = out_v + T*D;

    hipLaunchKernelGGL(k_front, dim3(292),       dim3(256), 0, stream,
                       vf, vpos, cw, cb, tf, tpos, Wi, wt, wv, ve, tn, ut, uv);
    hipLaunchKernelGGL(k_mid,   dim3(392),       dim3(256), 0, stream, ve, W1, b1, tn, bil, f1, q);
    hipLaunchKernelGGL(k_gnn,   dim3(192),       dim3(256), 0, stream, tn, q, lw, lb, W2, tg, f2);
    hipLaunchKernelGGL(k_score, dim3(24, 12, 4), dim3(256), 0, stream, f1, f2, ut, uv, stp, svp);
    hipLaunchKernelGGL(k_att,   dim3(288),       dim3(256), 0, stream, stp, svp, tg, ve, vf, tf, out_v, out_t);
}

// Round 6
// 104.993 us; speedup vs baseline: 1.3459x; 1.3459x over previous
//
#include <hip/hip_runtime.h>
#include <math.h>

#define D  256
#define T  768
#define N  384
#define FD 512

#define DOT4(A,B) ((A).x*(B).x + (A).y*(B).y + (A).z*(B).z + (A).w*(B).w)

// ---------- node 1: k_front ------------------------------------------------------
// blocks [0,192)   : conv1d tile-GEMM, 32t x 32o, K = 4 chunks x (64i x 3k)
// blocks [192,288) : text row-l2-normalize
// blocks [288,292) : ut/uv = Wi.T @ wt/wv
__global__ __launch_bounds__(256) void k_front(
    const float* __restrict__ vf, const float* __restrict__ vpos,
    const float* __restrict__ cw, const float* __restrict__ cb,
    const float* __restrict__ tf, const float* __restrict__ tpos,
    const float* __restrict__ Wi, const float* __restrict__ wt,
    const float* __restrict__ wv,
    float* __restrict__ ve, float* __restrict__ tn,
    float* __restrict__ ut, float* __restrict__ uv)
{
    __shared__ float As[34][68];        // vpe rows t0-1 .. t0+32, one 64-col chunk
    __shared__ float Bs[3][32][68];     // cw de-interleaved: [k][o][i]
    const int b = blockIdx.x, tid = threadIdx.x;

    if (b < 192) {
        const int t0 = (b >> 3) * 32;   // 24 t-tiles
        const int o0 = (b & 7) * 32;    // 8 o-tiles
        const int p  = tid >> 4;        // 0..15 -> t-rows 2p, 2p+1
        const int oA = tid & 15;        // o-cols oA, oA+16
        float acc00 = 0.f, acc01 = 0.f, acc10 = 0.f, acc11 = 0.f;

        for (int c = 0; c < 4; ++c) {
            const int i0 = c << 6;
            __syncthreads();
            // stage As: 34 rows x 16 float4 = 544 units
#pragma unroll
            for (int s = 0; s < 3; ++s) {
                int u = tid + (s << 8);
                if (u < 544) {
                    int r = u >> 4, uq = u & 15;
                    int gr = t0 - 1 + r;
                    float4 v = make_float4(0.f, 0.f, 0.f, 0.f);
                    if (gr >= 0 && gr < T) {
                        float4 a = *(const float4*)&vf[gr*D + i0 + uq*4];
                        float4 pz = *(const float4*)&vpos[gr*D + i0 + uq*4];
                        v = make_float4(a.x+pz.x, a.y+pz.y, a.z+pz.z, a.w+pz.w);
                    }
                    *(float4*)&As[r][uq*4] = v;
                }
            }
            // stage Bs: 32 o-rows x 48 float4 = 1536 units (coalesced loads,
            // de-interleave (i*3+k) -> [k][o][i] via scalar LDS writes)
#pragma unroll
            for (int s = 0; s < 6; ++s) {
                int u = tid + (s << 8);
                int oc = u / 48, uq = u - oc * 48;
                float4 v = *(const float4*)&cw[(o0 + oc)*768 + i0*3 + uq*4];
                int j0 = uq * 4;
                Bs[(j0    ) % 3][oc][(j0    ) / 3] = v.x;
                Bs[(j0 + 1) % 3][oc][(j0 + 1) / 3] = v.y;
                Bs[(j0 + 2) % 3][oc][(j0 + 2) / 3] = v.z;
                Bs[(j0 + 3) % 3][oc][(j0 + 3) / 3] = v.w;
            }
            __syncthreads();
#pragma unroll 4
            for (int i4 = 0; i4 < 16; ++i4) {
                float4 ar0 = *(const float4*)&As[2*p    ][i4*4];
                float4 ar1 = *(const float4*)&As[2*p + 1][i4*4];
                float4 ar2 = *(const float4*)&As[2*p + 2][i4*4];
                float4 ar3 = *(const float4*)&As[2*p + 3][i4*4];
                float4 b00 = *(const float4*)&Bs[0][oA   ][i4*4];
                float4 b01 = *(const float4*)&Bs[0][oA+16][i4*4];
                float4 b10 = *(const float4*)&Bs[1][oA   ][i4*4];
                float4 b11 = *(const float4*)&Bs[1][oA+16][i4*4];
                float4 b20 = *(const float4*)&Bs[2][oA   ][i4*4];
                float4 b21 = *(const float4*)&Bs[2][oA+16][i4*4];
                acc00 += DOT4(ar0,b00) + DOT4(ar1,b10) + DOT4(ar2,b20);
                acc01 += DOT4(ar0,b01) + DOT4(ar1,b11) + DOT4(ar2,b21);
                acc10 += DOT4(ar1,b00) + DOT4(ar2,b10) + DOT4(ar3,b20);
                acc11 += DOT4(ar1,b01) + DOT4(ar2,b11) + DOT4(ar3,b21);
            }
        }
        const float bia = cb[o0 + oA], bib = cb[o0 + oA + 16];
        const int t = t0 + 2*p;
        ve[t*D + o0 + oA]          = fmaxf(acc00 + bia, 0.f);
        ve[t*D + o0 + oA + 16]     = fmaxf(acc01 + bib, 0.f);
        ve[(t+1)*D + o0 + oA]      = fmaxf(acc10 + bia, 0.f);
        ve[(t+1)*D + o0 + oA + 16] = fmaxf(acc11 + bib, 0.f);
    } else if (b < 288) {
        const int wid = tid >> 6, lane = tid & 63;
        const int r = (b - 192)*4 + wid;
        float v[4]; float ss = 0.f;
#pragma unroll
        for (int kk = 0; kk < 4; ++kk) {
            v[kk] = tf[r*D + lane + 64*kk] + tpos[r*D + lane + 64*kk];
            ss += v[kk]*v[kk];
        }
#pragma unroll
        for (int off = 1; off < 64; off <<= 1) ss += __shfl_xor(ss, off);
        float inv = 1.0f / fmaxf(sqrtf(ss), 1e-12f);
#pragma unroll
        for (int kk = 0; kk < 4; ++kk) tn[r*D + lane + 64*kk] = v[kk] * inv;
    } else {
        float* wsm = &As[0][0];
        const int which = b - 288;                  // 0,1 -> ut ; 2,3 -> uv
        const float* w = (which < 2) ? wt : wv;
        float* u = (which < 2) ? ut : uv;
        const int f = ((which & 1) << 8) + tid;
        wsm[tid] = w[tid];
        __syncthreads();
        float s = 0.f;
#pragma unroll 4
        for (int d = 0; d < D; ++d) s += wsm[d] * Wi[d*FD + f];
        u[f] = s;
    }
}

// ---------- node 2: k_mid --------------------------------------------------------
// blocks [0,384)   : f1 = ve @ W1.T + b1  (32t x 32f tiles, K=256)
// blocks [384,392) : q = (mean_rows tn) @ bil_w
// blocks [392,488) : tl = tn @ lin_w.T + lin_b  (32n x 32o tiles, K=256)
__global__ __launch_bounds__(256) void k_mid(
    const float* __restrict__ ve, const float* __restrict__ W1,
    const float* __restrict__ b1, const float* __restrict__ tn,
    const float* __restrict__ bil, const float* __restrict__ lin_w,
    const float* __restrict__ lin_b,
    float* __restrict__ f1, float* __restrict__ q, float* __restrict__ tl)
{
    __shared__ float As[32][68];
    __shared__ float Bs[32][68];
    const int b = blockIdx.x, tid = threadIdx.x;

    if (b < 384) {
        const int t0 = (b >> 4) * 32;
        const int f0 = (b & 15) * 32;
        const int tA = tid >> 4, fA = tid & 15;
        float acc00 = 0.f, acc01 = 0.f, acc10 = 0.f, acc11 = 0.f;
        for (int c = 0; c < 4; ++c) {
            const int d0 = c << 6;
            __syncthreads();
            const int kc = tid & 63, g = tid >> 6;
#pragma unroll
            for (int it = 0; it < 8; ++it) {
                int tt = g + it*4;
                As[tt][kc] = ve[(t0 + tt)*D + d0 + kc];
                Bs[tt][kc] = W1[(f0 + tt)*D + d0 + kc];
            }
            __syncthreads();
#pragma unroll
            for (int kc4 = 0; kc4 < 16; ++kc4) {
                float4 a0 = *(const float4*)&As[tA][kc4*4];
                float4 a1 = *(const float4*)&As[tA+16][kc4*4];
                float4 b0 = *(const float4*)&Bs[fA][kc4*4];
                float4 b1 = *(const float4*)&Bs[fA+16][kc4*4];
                acc00 += DOT4(a0, b0); acc01 += DOT4(a0, b1);
                acc10 += DOT4(a1, b0); acc11 += DOT4(a1, b1);
            }
        }
        const float bia = b1[f0 + fA], bib = b1[f0 + fA + 16];
        f1[(t0 + tA)*FD + f0 + fA]           = acc00 + bia;
        f1[(t0 + tA)*FD + f0 + fA + 16]      = acc01 + bib;
        f1[(t0 + tA + 16)*FD + f0 + fA]      = acc10 + bia;
        f1[(t0 + tA + 16)*FD + f0 + fA + 16] = acc11 + bib;
    } else if (b < 392) {
        float* tb = &As[0][0];              // 256 floats
        float (*qp)[32] = (float(*)[32])&Bs[0][0];   // 8x32
        const int bq = b - 384;
        float s = 0.f;
#pragma unroll 8
        for (int n = 0; n < N; ++n) s += tn[n*D + tid];
        tb[tid] = s * (1.0f / (float)N);
        __syncthreads();
        const int o = tid & 31, dg = tid >> 5;
        float p = 0.f;
#pragma unroll 8
        for (int d = dg*32; d < dg*32 + 32; ++d) p += tb[d] * bil[d*D + bq*32 + o];
        qp[dg][o] = p;
        __syncthreads();
        if (tid < 32) {
            float acc = 0.f;
#pragma unroll
            for (int kk = 0; kk < 8; ++kk) acc += qp[kk][tid];
            q[bq*32 + tid] = acc;
        }
    } else {
        const int bb = b - 392;
        const int n0 = (bb >> 3) * 32;      // 12 n-tiles
        const int o0 = (bb & 7) * 32;       // 8 o-tiles
        const int tA = tid >> 4, oA = tid & 15;
        float acc00 = 0.f, acc01 = 0.f, acc10 = 0.f, acc11 = 0.f;
        for (int c = 0; c < 4; ++c) {
            const int d0 = c << 6;
            __syncthreads();
            const int kc = tid & 63, g = tid >> 6;
#pragma unroll
            for (int it = 0; it < 8; ++it) {
                int tt = g + it*4;
                As[tt][kc] = tn[(n0 + tt)*D + d0 + kc];
                Bs[tt][kc] = lin_w[(o0 + tt)*D + d0 + kc];
            }
            __syncthreads();
#pragma unroll
            for (int kc4 = 0; kc4 < 16; ++kc4) {
                float4 a0 = *(const float4*)&As[tA][kc4*4];
                float4 a1 = *(const float4*)&As[tA+16][kc4*4];
                float4 b0 = *(const float4*)&Bs[oA][kc4*4];
                float4 b1 = *(const float4*)&Bs[oA+16][kc4*4];
                acc00 += DOT4(a0, b0); acc01 += DOT4(a0, b1);
                acc10 += DOT4(a1, b0); acc11 += DOT4(a1, b1);
            }
        }
        const float bia = lin_b[o0 + oA], bib = lin_b[o0 + oA + 16];
        tl[(n0 + tA)*D + o0 + oA]           = acc00 + bia;
        tl[(n0 + tA)*D + o0 + oA + 16]      = acc01 + bib;
        tl[(n0 + tA + 16)*D + o0 + oA]      = acc10 + bia;
        tl[(n0 + tA + 16)*D + o0 + oA + 16] = acc11 + bib;
    }
}

// ---------- node 3: k_f2  (sigmoid gate recompute + tg + f2 = tg@W2.T) ----------
__global__ __launch_bounds__(256) void k_f2(
    const float* __restrict__ tn, const float* __restrict__ q,
    const float* __restrict__ tl, const float* __restrict__ W2,
    float* __restrict__ tg, float* __restrict__ f2)
{
    __shared__ float As[32][68];
    __shared__ float Bs[32][68];
    __shared__ float wsm[32];
    __shared__ float qs[D];
    const int tid = threadIdx.x;
    const int n0 = (blockIdx.x >> 4) * 32;   // 12 n-tiles
    const int f0 = (blockIdx.x & 15) * 32;   // 16 f-tiles

    qs[tid] = q[tid];
    __syncthreads();
    {   // w[r] = sigmoid(tn[n0+r] . q), 8 lanes per row
        const int r = tid >> 3, j = tid & 7;
        const float* row = tn + (n0 + r)*D + j*32;
        float p = 0.f;
#pragma unroll
        for (int m4 = 0; m4 < 8; ++m4) {
            float4 a = *(const float4*)&row[m4*4];
            float4 qq = *(const float4*)&qs[j*32 + m4*4];
            p += DOT4(a, qq);
        }
        p += __shfl_xor(p, 1); p += __shfl_xor(p, 2); p += __shfl_xor(p, 4);
        if (j == 0) wsm[r] = 1.0f / (1.0f + expf(-p));
    }
    __syncthreads();

    const int tA = tid >> 4, fA = tid & 15;
    float acc00 = 0.f, acc01 = 0.f, acc10 = 0.f, acc11 = 0.f;
    for (int c = 0; c < 4; ++c) {
        const int d0 = c << 6;
        __syncthreads();
        const int kc = tid & 63, g = tid >> 6;
#pragma unroll
        for (int it = 0; it < 8; ++it) {
            int tt = g + it*4;
            float av = wsm[tt] * tl[(n0 + tt)*D + d0 + kc];
            As[tt][kc] = av;
            if (f0 == 0) tg[(n0 + tt)*D + d0 + kc] = av;
            Bs[tt][kc] = W2[(f0 + tt)*D + d0 + kc];
        }
        __syncthreads();
#pragma unroll
        for (int kc4 = 0; kc4 < 16; ++kc4) {
            float4 a0 = *(const float4*)&As[tA][kc4*4];
            float4 a1 = *(const float4*)&As[tA+16][kc4*4];
            float4 b0 = *(const float4*)&Bs[fA][kc4*4];
            float4 b1 = *(const float4*)&Bs[fA+16][kc4*4];
            acc00 += DOT4(a0, b0); acc01 += DOT4(a0, b1);
            acc10 += DOT4(a1, b0); acc11 += DOT4(a1, b1);
        }
    }
    f2[(n0 + tA)*FD + f0 + fA]           = acc00;
    f2[(n0 + tA)*FD + f0 + fA + 16]      = acc01;
    f2[(n0 + tA + 16)*FD + f0 + fA]      = acc10;
    f2[(n0 + tA + 16)*FD + f0 + fA + 16] = acc11;
}

// ---------- node 4: k_score  (FD split over blockIdx.z, partial outputs) ----------
__global__ __launch_bounds__(256) void k_score(
    const float* __restrict__ f1, const float* __restrict__ f2,
    const float* __restrict__ ut, const float* __restrict__ uv,
    float* __restrict__ stp, float* __restrict__ svp)
{
    __shared__ float f1s[32][132];
    __shared__ float f2s[32][132];
    __shared__ float us_t[128];
    __shared__ float us_v[128];
    const int tid = threadIdx.x;
    const int t0 = blockIdx.x * 32, n0 = blockIdx.y * 32, c = blockIdx.z;

    if (tid < 128) { us_t[tid] = ut[c*128 + tid]; us_v[tid] = uv[c*128 + tid]; }
    for (int j = tid; j < 1024; j += 256) {
        int r = j >> 5, c4 = (j & 31) * 4;
        *(float4*)&f1s[r][c4] = *(const float4*)&f1[(t0 + r)*FD + c*128 + c4];
        *(float4*)&f2s[r][c4] = *(const float4*)&f2[(n0 + r)*FD + c*128 + c4];
    }
    __syncthreads();

    const int tA = 2 * (tid >> 4);
    const int nA = tid & 15;

    float at00=0.f, at01=0.f, at10=0.f, at11=0.f;
    float av00=0.f, av01=0.f, av10=0.f, av11=0.f;

#pragma unroll 8
    for (int fq = 0; fq < 32; ++fq) {
        float4 u_t = *(const float4*)&us_t[fq*4];
        float4 u_v = *(const float4*)&us_v[fq*4];
        float4 a0 = *(const float4*)&f1s[tA][fq*4];
        float4 a1 = *(const float4*)&f1s[tA+1][fq*4];
        float4 b0 = *(const float4*)&f2s[nA][fq*4];
        float4 b1 = *(const float4*)&f2s[nA+16][fq*4];
#pragma unroll
        for (int e = 0; e < 4; ++e) {
            float ue_t = ((const float*)&u_t)[e];
            float ue_v = ((const float*)&u_v)[e];
            float a0e = ((const float*)&a0)[e], a1e = ((const float*)&a1)[e];
            float b0e = ((const float*)&b0)[e], b1e = ((const float*)&b1)[e];
            float h00 = fmaxf(a0e + b0e, 0.f);
            float h01 = fmaxf(a0e + b1e, 0.f);
            float h10 = fmaxf(a1e + b0e, 0.f);
            float h11 = fmaxf(a1e + b1e, 0.f);
            at00 += h00*ue_t; av00 += h00*ue_v;
            at01 += h01*ue_t; av01 += h01*ue_v;
            at10 += h10*ue_t; av10 += h10*ue_v;
            at11 += h11*ue_t; av11 += h11*ue_v;
        }
    }
    const int t = t0 + tA, n = n0 + nA;
    float* stz = stp + c * (T*N);
    float* svz = svp + c * (N*T);
    stz[t*N + n]        = at00;  stz[t*N + n + 16]     = at01;
    stz[(t+1)*N + n]    = at10;  stz[(t+1)*N + n + 16] = at11;
    *(float2*)&svz[n*T + t]      = make_float2(av00, av10);
    *(float2*)&svz[(n+16)*T + t] = make_float2(av01, av11);
}

// ---------- node 5: k_att  (combine partials + softmax + context + epilogue) ------
__global__ __launch_bounds__(256) void k_att(
    const float* __restrict__ stp, const float* __restrict__ svp,
    const float* __restrict__ tg, const float* __restrict__ ve,
    const float* __restrict__ vf, const float* __restrict__ tf,
    float* __restrict__ out_v, float* __restrict__ out_t)
{
    __shared__ float attb[768][8];
    __shared__ float red[4][8];
    __shared__ float ptA[4][8][64];
    __shared__ float ptB[4][8][64];
    const int tid = threadIdx.x;
    const int oo = tid & 63, g = tid >> 6;

    if (blockIdx.x < 192) {
        const int bx = blockIdx.x >> 1, h = blockIdx.x & 1;
        const int t0 = bx * 8;
        const int oA = h*128 + oo, oB = oA + 64;

        float v1[8], v2[8];
#pragma unroll
        for (int r = 0; r < 8; ++r) {
            const float* p = stp + (t0 + r)*N + tid;
            v1[r] = p[0] + p[T*N] + p[2*T*N] + p[3*T*N];
            if (tid < 128) {
                const float* p2 = p + 256;
                v2[r] = p2[0] + p2[T*N] + p2[2*T*N] + p2[3*T*N];
            } else v2[r] = -1e30f;
        }
        float m[8], si[8];
#pragma unroll
        for (int r = 0; r < 8; ++r) {
            float mm = fmaxf(v1[r], v2[r]);
#pragma unroll
            for (int off = 1; off < 64; off <<= 1) mm = fmaxf(mm, __shfl_xor(mm, off));
            if (oo == 0) red[g][r] = mm;
        }
        __syncthreads();
#pragma unroll
        for (int r = 0; r < 8; ++r)
            m[r] = fmaxf(fmaxf(red[0][r], red[1][r]), fmaxf(red[2][r], red[3][r]));
        __syncthreads();
        float e1[8], e2[8];
#pragma unroll
        for (int r = 0; r < 8; ++r) {
            e1[r] = expf(v1[r] - m[r]);
            e2[r] = (tid < 128) ? expf(v2[r] - m[r]) : 0.f;
            float ss = e1[r] + e2[r];
#pragma unroll
            for (int off = 1; off < 64; off <<= 1) ss += __shfl_xor(ss, off);
            if (oo == 0) red[g][r] = ss;
        }
        __syncthreads();
#pragma unroll
        for (int r = 0; r < 8; ++r)
            si[r] = 1.0f / (red[0][r] + red[1][r] + red[2][r] + red[3][r]);
#pragma unroll
        for (int r = 0; r < 8; ++r) {
            attb[tid][r] = e1[r] * si[r];
            if (tid < 128) attb[tid + 256][r] = e2[r] * si[r];
        }
        __syncthreads();

        float accA[8] = {0.f,0.f,0.f,0.f,0.f,0.f,0.f,0.f};
        float accB[8] = {0.f,0.f,0.f,0.f,0.f,0.f,0.f,0.f};
#pragma unroll 4
        for (int n = g; n < N; n += 4) {
            float4 a0 = *(const float4*)&attb[n][0];
            float4 a1 = *(const float4*)&attb[n][4];
            float tvA = tg[n*D + oA], tvB = tg[n*D + oB];
            accA[0] += a0.x*tvA; accA[1] += a0.y*tvA; accA[2] += a0.z*tvA; accA[3] += a0.w*tvA;
            accA[4] += a1.x*tvA; accA[5] += a1.y*tvA; accA[6] += a1.z*tvA; accA[7] += a1.w*tvA;
            accB[0] += a0.x*tvB; accB[1] += a0.y*tvB; accB[2] += a0.z*tvB; accB[3] += a0.w*tvB;
            accB[4] += a1.x*tvB; accB[5] += a1.y*tvB; accB[6] += a1.z*tvB; accB[7] += a1.w*tvB;
        }
#pragma unroll
        for (int r = 0; r < 8; ++r) { ptA[g][r][oo] = accA[r]; ptB[g][r][oo] = accB[r]; }
        __syncthreads();
#pragma unroll
        for (int rr = g; rr < 8; rr += 4) {
            float sA = ptA[0][rr][oo] + ptA[1][rr][oo] + ptA[2][rr][oo] + ptA[3][rr][oo];
            float sB = ptB[0][rr][oo] + ptB[1][rr][oo] + ptB[2][rr][oo] + ptB[3][rr][oo];
            int t = t0 + rr;
            out_v[t*D + oA] = 0.5f*sA + 0.5f*ve[t*D + oA] + vf[t*D + oA];
            out_v[t*D + oB] = 0.5f*sB + 0.5f*ve[t*D + oB] + vf[t*D + oB];
        }
    } else {
        const int b2 = blockIdx.x - 192;
        const int bx = b2 >> 1, h = b2 & 1;
        const int n0 = bx * 8;
        const int oA = h*128 + oo, oB = oA + 64;

        float v1[8], v2[8], v3[8];
#pragma unroll
        for (int r = 0; r < 8; ++r) {
            const float* p = svp + (n0 + r)*T + tid;
            v1[r] = p[0]   + p[N*T]       + p[2*N*T]       + p[3*N*T];
            v2[r] = p[256] + p[N*T + 256] + p[2*N*T + 256] + p[3*N*T + 256];
            v3[r] = p[512] + p[N*T + 512] + p[2*N*T + 512] + p[3*N*T + 512];
        }
        float m[8], si[8];
#pragma unroll
        for (int r = 0; r < 8; ++r) {
            float mm = fmaxf(fmaxf(v1[r], v2[r]), v3[r]);
#pragma unroll
            for (int off = 1; off < 64; off <<= 1) mm = fmaxf(mm, __shfl_xor(mm, off));
            if (oo == 0) red[g][r] = mm;
        }
        __syncthreads();
#pragma unroll
        for (int r = 0; r < 8; ++r)
            m[r] = fmaxf(fmaxf(red[0][r], red[1][r]), fmaxf(red[2][r], red[3][r]));
        __syncthreads();
        float e1[8], e2[8], e3[8];
#pragma unroll
        for (int r = 0; r < 8; ++r) {
            e1[r] = expf(v1[r] - m[r]);
            e2[r] = expf(v2[r] - m[r]);
            e3[r] = expf(v3[r] - m[r]);
            float ss = e1[r] + e2[r] + e3[r];
#pragma unroll
            for (int off = 1; off < 64; off <<= 1) ss += __shfl_xor(ss, off);
            if (oo == 0) red[g][r] = ss;
        }
        __syncthreads();
#pragma unroll
        for (int r = 0; r < 8; ++r)
            si[r] = 1.0f / (red[0][r] + red[1][r] + red[2][r] + red[3][r]);
#pragma unroll
        for (int r = 0; r < 8; ++r) {
            attb[tid][r]       = e1[r] * si[r];
            attb[tid + 256][r] = e2[r] * si[r];
            attb[tid + 512][r] = e3[r] * si[r];
        }
        __syncthreads();

        float accA[8] = {0.f,0.f,0.f,0.f,0.f,0.f,0.f,0.f};
        float accB[8] = {0.f,0.f,0.f,0.f,0.f,0.f,0.f,0.f};
#pragma unroll 4
        for (int t = g; t < T; t += 4) {
            float4 a0 = *(const float4*)&attb[t][0];
            float4 a1 = *(const float4*)&attb[t][4];
            float vvA = ve[t*D + oA], vvB = ve[t*D + oB];
            accA[0] += a0.x*vvA; accA[1] += a0.y*vvA; accA[2] += a0.z*vvA; accA[3] += a0.w*vvA;
            accA[4] += a1.x*vvA; accA[5] += a1.y*vvA; accA[6] += a1.z*vvA; accA[7] += a1.w*vvA;
            accB[0] += a0.x*vvB; accB[1] += a0.y*vvB; accB[2] += a0.z*vvB; accB[3] += a0.w*vvB;
            accB[4] += a1.x*vvB; accB[5] += a1.y*vvB; accB[6] += a1.z*vvB; accB[7] += a1.w*vvB;
        }
#pragma unroll
        for (int r = 0; r < 8; ++r) { ptA[g][r][oo] = accA[r]; ptB[g][r][oo] = accB[r]; }
        __syncthreads();
#pragma unroll
        for (int rr = g; rr < 8; rr += 4) {
            float sA = ptA[0][rr][oo] + ptA[1][rr][oo] + ptA[2][rr][oo] + ptA[3][rr][oo];
            float sB = ptB[0][rr][oo] + ptB[1][rr][oo] + ptB[2][rr][oo] + ptB[3][rr][oo];
            int n = n0 + rr;
            out_t[n*D + oA] = 0.5f*sA + 0.5f*tg[n*D + oA] + tf[n*D + oA];
            out_t[n*D + oB] = 0.5f*sB + 0.5f*tg[n*D + oB] + tf[n*D + oB];
        }
    }
}

extern "C" void kernel_launch(void* const* d_in, const int* in_sizes, int n_in,
                              void* d_out, int out_size, void* d_ws, size_t ws_size,
                              hipStream_t stream)
{
    (void)in_sizes; (void)n_in; (void)out_size; (void)ws_size;
    const float* vf   = (const float*)d_in[0];
    const float* tf   = (const float*)d_in[1];
    const float* vpos = (const float*)d_in[2];
    const float* tpos = (const float*)d_in[3];
    const float* cw   = (const float*)d_in[4];
    const float* cb   = (const float*)d_in[5];
    const float* bil  = (const float*)d_in[6];
    const float* lw   = (const float*)d_in[7];
    const float* lb   = (const float*)d_in[8];
    const float* W1   = (const float*)d_in[9];
    const float* b1   = (const float*)d_in[10];
    const float* W2   = (const float*)d_in[11];
    const float* Wi   = (const float*)d_in[12];
    // d_in[13]=bi, d_in[15]=bt, d_in[17]=bv: softmax-invariant constant shifts -> unused
    const float* wt   = (const float*)d_in[14];
    const float* wv   = (const float*)d_in[16];

    float* ws  = (float*)d_ws;
    float* ve  = ws;                // T*D
    float* tn  = ve + T*D;          // N*D
    float* tg  = tn + N*D;          // N*D
    float* tl  = tg + N*D;          // N*D
    float* f1  = tl + N*D;          // T*FD
    float* f2  = f1 + T*FD;         // N*FD
    float* q   = f2 + N*FD;         // D
    float* ut  = q + D;             // FD
    float* uv  = ut + FD;           // FD
    float* stp = uv + FD;           // 4*T*N
    float* svp = stp + 4*T*N;       // 4*N*T

    float* out_v = (float*)d_out;
    float* out_t = out_v + T*D;

    hipLaunchKernelGGL(k_front, dim3(292),       dim3(256), 0, stream,
                       vf, vpos, cw, cb, tf, tpos, Wi, wt, wv, ve, tn, ut, uv);
    hipLaunchKernelGGL(k_mid,   dim3(488),       dim3(256), 0, stream,
                       ve, W1, b1, tn, bil, lw, lb, f1, q, tl);
    hipLaunchKernelGGL(k_f2,    dim3(192),       dim3(256), 0, stream, tn, q, tl, W2, tg, f2);
    hipLaunchKernelGGL(k_score, dim3(24, 12, 4), dim3(256), 0, stream, f1, f2, ut, uv, stp, svp);
    hipLaunchKernelGGL(k_att,   dim3(288),       dim3(256), 0, stream, stp, svp, tg, ve, vf, tf, out_v, out_t);
}

// Round 7
// 102.406 us; speedup vs baseline: 1.3799x; 1.0253x over previous
//
#include <hip/hip_runtime.h>
#include <math.h>

#define D  256
#define T  768
#define N  384
#define FD 512

#define DOT4(A,B) ((A).x*(B).x + (A).y*(B).y + (A).z*(B).z + (A).w*(B).w)

// ---------- node 1: k_front ------------------------------------------------------
// blocks [0,192)   : conv1d tile-GEMM, 32t x 32o, K = 4 chunks x (64i x 3k)
// blocks [192,288) : text row-l2-normalize
// blocks [288,292) : ut/uv = Wi.T @ wt/wv
__global__ __launch_bounds__(256) void k_front(
    const float* __restrict__ vf, const float* __restrict__ vpos,
    const float* __restrict__ cw, const float* __restrict__ cb,
    const float* __restrict__ tf, const float* __restrict__ tpos,
    const float* __restrict__ Wi, const float* __restrict__ wt,
    const float* __restrict__ wv,
    float* __restrict__ ve, float* __restrict__ tn,
    float* __restrict__ ut, float* __restrict__ uv)
{
    __shared__ float As[34][68];        // vpe rows t0-1 .. t0+32, one 64-col chunk
    __shared__ float Bs[3][32][68];     // cw de-interleaved: [k][o][i]
    const int b = blockIdx.x, tid = threadIdx.x;

    if (b < 192) {
        const int t0 = (b >> 3) * 32;   // 24 t-tiles
        const int o0 = (b & 7) * 32;    // 8 o-tiles
        const int p  = tid >> 4;        // 0..15 -> t-rows 2p, 2p+1
        const int oA = tid & 15;        // o-cols oA, oA+16
        float acc00 = 0.f, acc01 = 0.f, acc10 = 0.f, acc11 = 0.f;

        for (int c = 0; c < 4; ++c) {
            const int i0 = c << 6;
            __syncthreads();
#pragma unroll
            for (int s = 0; s < 3; ++s) {
                int u = tid + (s << 8);
                if (u < 544) {
                    int r = u >> 4, uq = u & 15;
                    int gr = t0 - 1 + r;
                    float4 v = make_float4(0.f, 0.f, 0.f, 0.f);
                    if (gr >= 0 && gr < T) {
                        float4 a = *(const float4*)&vf[gr*D + i0 + uq*4];
                        float4 pz = *(const float4*)&vpos[gr*D + i0 + uq*4];
                        v = make_float4(a.x+pz.x, a.y+pz.y, a.z+pz.z, a.w+pz.w);
                    }
                    *(float4*)&As[r][uq*4] = v;
                }
            }
#pragma unroll
            for (int s = 0; s < 6; ++s) {
                int u = tid + (s << 8);
                int oc = u / 48, uq = u - oc * 48;
                float4 v = *(const float4*)&cw[(o0 + oc)*768 + i0*3 + uq*4];
                int j0 = uq * 4;
                Bs[(j0    ) % 3][oc][(j0    ) / 3] = v.x;
                Bs[(j0 + 1) % 3][oc][(j0 + 1) / 3] = v.y;
                Bs[(j0 + 2) % 3][oc][(j0 + 2) / 3] = v.z;
                Bs[(j0 + 3) % 3][oc][(j0 + 3) / 3] = v.w;
            }
            __syncthreads();
#pragma unroll 4
            for (int i4 = 0; i4 < 16; ++i4) {
                float4 ar0 = *(const float4*)&As[2*p    ][i4*4];
                float4 ar1 = *(const float4*)&As[2*p + 1][i4*4];
                float4 ar2 = *(const float4*)&As[2*p + 2][i4*4];
                float4 ar3 = *(const float4*)&As[2*p + 3][i4*4];
                float4 b00 = *(const float4*)&Bs[0][oA   ][i4*4];
                float4 b01 = *(const float4*)&Bs[0][oA+16][i4*4];
                float4 b10 = *(const float4*)&Bs[1][oA   ][i4*4];
                float4 b11 = *(const float4*)&Bs[1][oA+16][i4*4];
                float4 b20 = *(const float4*)&Bs[2][oA   ][i4*4];
                float4 b21 = *(const float4*)&Bs[2][oA+16][i4*4];
                acc00 += DOT4(ar0,b00) + DOT4(ar1,b10) + DOT4(ar2,b20);
                acc01 += DOT4(ar0,b01) + DOT4(ar1,b11) + DOT4(ar2,b21);
                acc10 += DOT4(ar1,b00) + DOT4(ar2,b10) + DOT4(ar3,b20);
                acc11 += DOT4(ar1,b01) + DOT4(ar2,b11) + DOT4(ar3,b21);
            }
        }
        const float bia = cb[o0 + oA], bib = cb[o0 + oA + 16];
        const int t = t0 + 2*p;
        ve[t*D + o0 + oA]          = fmaxf(acc00 + bia, 0.f);
        ve[t*D + o0 + oA + 16]     = fmaxf(acc01 + bib, 0.f);
        ve[(t+1)*D + o0 + oA]      = fmaxf(acc10 + bia, 0.f);
        ve[(t+1)*D + o0 + oA + 16] = fmaxf(acc11 + bib, 0.f);
    } else if (b < 288) {
        const int wid = tid >> 6, lane = tid & 63;
        const int r = (b - 192)*4 + wid;
        float v[4]; float ss = 0.f;
#pragma unroll
        for (int kk = 0; kk < 4; ++kk) {
            v[kk] = tf[r*D + lane + 64*kk] + tpos[r*D + lane + 64*kk];
            ss += v[kk]*v[kk];
        }
#pragma unroll
        for (int off = 1; off < 64; off <<= 1) ss += __shfl_xor(ss, off);
        float inv = 1.0f / fmaxf(sqrtf(ss), 1e-12f);
#pragma unroll
        for (int kk = 0; kk < 4; ++kk) tn[r*D + lane + 64*kk] = v[kk] * inv;
    } else {
        float* wsm = &As[0][0];
        const int which = b - 288;                  // 0,1 -> ut ; 2,3 -> uv
        const float* w = (which < 2) ? wt : wv;
        float* u = (which < 2) ? ut : uv;
        const int f = ((which & 1) << 8) + tid;
        wsm[tid] = w[tid];
        __syncthreads();
        float s = 0.f;
#pragma unroll 4
        for (int d = 0; d < D; ++d) s += wsm[d] * Wi[d*FD + f];
        u[f] = s;
    }
}

// ---------- node 2: k_mid --------------------------------------------------------
// blocks [0,384)   : f1 = ve @ W1.T + b1  (32t x 32f tiles, K=256)
// blocks [384,392) : q = (mean_rows tn) @ bil_w
// blocks [392,488) : tl = tn @ lin_w.T + lin_b  (32n x 32o tiles, K=256)
__global__ __launch_bounds__(256) void k_mid(
    const float* __restrict__ ve, const float* __restrict__ W1,
    const float* __restrict__ b1, const float* __restrict__ tn,
    const float* __restrict__ bil, const float* __restrict__ lin_w,
    const float* __restrict__ lin_b,
    float* __restrict__ f1, float* __restrict__ q, float* __restrict__ tl)
{
    __shared__ float As[32][68];
    __shared__ float Bs[32][68];
    const int b = blockIdx.x, tid = threadIdx.x;

    if (b < 384) {
        const int t0 = (b >> 4) * 32;
        const int f0 = (b & 15) * 32;
        const int tA = tid >> 4, fA = tid & 15;
        float acc00 = 0.f, acc01 = 0.f, acc10 = 0.f, acc11 = 0.f;
        for (int c = 0; c < 4; ++c) {
            const int d0 = c << 6;
            __syncthreads();
            const int kc = tid & 63, g = tid >> 6;
#pragma unroll
            for (int it = 0; it < 8; ++it) {
                int tt = g + it*4;
                As[tt][kc] = ve[(t0 + tt)*D + d0 + kc];
                Bs[tt][kc] = W1[(f0 + tt)*D + d0 + kc];
            }
            __syncthreads();
#pragma unroll
            for (int kc4 = 0; kc4 < 16; ++kc4) {
                float4 a0 = *(const float4*)&As[tA][kc4*4];
                float4 a1 = *(const float4*)&As[tA+16][kc4*4];
                float4 b0 = *(const float4*)&Bs[fA][kc4*4];
                float4 b1 = *(const float4*)&Bs[fA+16][kc4*4];
                acc00 += DOT4(a0, b0); acc01 += DOT4(a0, b1);
                acc10 += DOT4(a1, b0); acc11 += DOT4(a1, b1);
            }
        }
        const float bia = b1[f0 + fA], bib = b1[f0 + fA + 16];
        f1[(t0 + tA)*FD + f0 + fA]           = acc00 + bia;
        f1[(t0 + tA)*FD + f0 + fA + 16]      = acc01 + bib;
        f1[(t0 + tA + 16)*FD + f0 + fA]      = acc10 + bia;
        f1[(t0 + tA + 16)*FD + f0 + fA + 16] = acc11 + bib;
    } else if (b < 392) {
        float* tb = &As[0][0];
        float (*qp)[32] = (float(*)[32])&Bs[0][0];
        const int bq = b - 384;
        float s = 0.f;
#pragma unroll 8
        for (int n = 0; n < N; ++n) s += tn[n*D + tid];
        tb[tid] = s * (1.0f / (float)N);
        __syncthreads();
        const int o = tid & 31, dg = tid >> 5;
        float p = 0.f;
#pragma unroll 8
        for (int d = dg*32; d < dg*32 + 32; ++d) p += tb[d] * bil[d*D + bq*32 + o];
        qp[dg][o] = p;
        __syncthreads();
        if (tid < 32) {
            float acc = 0.f;
#pragma unroll
            for (int kk = 0; kk < 8; ++kk) acc += qp[kk][tid];
            q[bq*32 + tid] = acc;
        }
    } else {
        const int bb = b - 392;
        const int n0 = (bb >> 3) * 32;
        const int o0 = (bb & 7) * 32;
        const int tA = tid >> 4, oA = tid & 15;
        float acc00 = 0.f, acc01 = 0.f, acc10 = 0.f, acc11 = 0.f;
        for (int c = 0; c < 4; ++c) {
            const int d0 = c << 6;
            __syncthreads();
            const int kc = tid & 63, g = tid >> 6;
#pragma unroll
            for (int it = 0; it < 8; ++it) {
                int tt = g + it*4;
                As[tt][kc] = tn[(n0 + tt)*D + d0 + kc];
                Bs[tt][kc] = lin_w[(o0 + tt)*D + d0 + kc];
            }
            __syncthreads();
#pragma unroll
            for (int kc4 = 0; kc4 < 16; ++kc4) {
                float4 a0 = *(const float4*)&As[tA][kc4*4];
                float4 a1 = *(const float4*)&As[tA+16][kc4*4];
                float4 b0 = *(const float4*)&Bs[oA][kc4*4];
                float4 b1 = *(const float4*)&Bs[oA+16][kc4*4];
                acc00 += DOT4(a0, b0); acc01 += DOT4(a0, b1);
                acc10 += DOT4(a1, b0); acc11 += DOT4(a1, b1);
            }
        }
        const float bia = lin_b[o0 + oA], bib = lin_b[o0 + oA + 16];
        tl[(n0 + tA)*D + o0 + oA]           = acc00 + bia;
        tl[(n0 + tA)*D + o0 + oA + 16]      = acc01 + bib;
        tl[(n0 + tA + 16)*D + o0 + oA]      = acc10 + bia;
        tl[(n0 + tA + 16)*D + o0 + oA + 16] = acc11 + bib;
    }
}

// ---------- node 3: k_f2  (sigmoid gate recompute + tg + f2 = tg@W2.T) ----------
__global__ __launch_bounds__(256) void k_f2(
    const float* __restrict__ tn, const float* __restrict__ q,
    const float* __restrict__ tl, const float* __restrict__ W2,
    float* __restrict__ tg, float* __restrict__ f2)
{
    __shared__ float As[32][68];
    __shared__ float Bs[32][68];
    __shared__ float wsm[32];
    __shared__ float qs[D];
    const int tid = threadIdx.x;
    const int n0 = (blockIdx.x >> 4) * 32;
    const int f0 = (blockIdx.x & 15) * 32;

    qs[tid] = q[tid];
    __syncthreads();
    {
        const int r = tid >> 3, j = tid & 7;
        const float* row = tn + (n0 + r)*D + j*32;
        float p = 0.f;
#pragma unroll
        for (int m4 = 0; m4 < 8; ++m4) {
            float4 a = *(const float4*)&row[m4*4];
            float4 qq = *(const float4*)&qs[j*32 + m4*4];
            p += DOT4(a, qq);
        }
        p += __shfl_xor(p, 1); p += __shfl_xor(p, 2); p += __shfl_xor(p, 4);
        if (j == 0) wsm[r] = 1.0f / (1.0f + expf(-p));
    }
    __syncthreads();

    const int tA = tid >> 4, fA = tid & 15;
    float acc00 = 0.f, acc01 = 0.f, acc10 = 0.f, acc11 = 0.f;
    for (int c = 0; c < 4; ++c) {
        const int d0 = c << 6;
        __syncthreads();
        const int kc = tid & 63, g = tid >> 6;
#pragma unroll
        for (int it = 0; it < 8; ++it) {
            int tt = g + it*4;
            float av = wsm[tt] * tl[(n0 + tt)*D + d0 + kc];
            As[tt][kc] = av;
            if (f0 == 0) tg[(n0 + tt)*D + d0 + kc] = av;
            Bs[tt][kc] = W2[(f0 + tt)*D + d0 + kc];
        }
        __syncthreads();
#pragma unroll
        for (int kc4 = 0; kc4 < 16; ++kc4) {
            float4 a0 = *(const float4*)&As[tA][kc4*4];
            float4 a1 = *(const float4*)&As[tA+16][kc4*4];
            float4 b0 = *(const float4*)&Bs[fA][kc4*4];
            float4 b1 = *(const float4*)&Bs[fA+16][kc4*4];
            acc00 += DOT4(a0, b0); acc01 += DOT4(a0, b1);
            acc10 += DOT4(a1, b0); acc11 += DOT4(a1, b1);
        }
    }
    f2[(n0 + tA)*FD + f0 + fA]           = acc00;
    f2[(n0 + tA)*FD + f0 + fA + 16]      = acc01;
    f2[(n0 + tA + 16)*FD + f0 + fA]      = acc10;
    f2[(n0 + tA + 16)*FD + f0 + fA + 16] = acc11;
}

// ---------- node 4: k_score  (64t x 32n tile, 4x2 cells/thread, z-split FD) ------
__global__ __launch_bounds__(256) void k_score(
    const float* __restrict__ f1, const float* __restrict__ f2,
    const float* __restrict__ ut, const float* __restrict__ uv,
    float* __restrict__ stp, float* __restrict__ svp)
{
    __shared__ float f1s[64][132];
    __shared__ float f2s[32][132];
    __shared__ float us_t[128];
    __shared__ float us_v[128];
    const int tid = threadIdx.x;
    const int t0 = blockIdx.x * 64, n0 = blockIdx.y * 32, c = blockIdx.z;

    if (tid < 128) { us_t[tid] = ut[c*128 + tid]; us_v[tid] = uv[c*128 + tid]; }
#pragma unroll
    for (int s = 0; s < 8; ++s) {
        int j = tid + (s << 8);
        int r = j >> 5, c4 = (j & 31) * 4;
        *(float4*)&f1s[r][c4] = *(const float4*)&f1[(t0 + r)*FD + c*128 + c4];
    }
#pragma unroll
    for (int s = 0; s < 4; ++s) {
        int j = tid + (s << 8);
        int r = j >> 5, c4 = (j & 31) * 4;
        *(float4*)&f2s[r][c4] = *(const float4*)&f2[(n0 + r)*FD + c*128 + c4];
    }
    __syncthreads();

    const int ti = tid >> 4, ni = tid & 15;   // rows ti+16m (m=0..3), cols ni+16mn
    float at[4][2] = {{0.f,0.f},{0.f,0.f},{0.f,0.f},{0.f,0.f}};
    float av[4][2] = {{0.f,0.f},{0.f,0.f},{0.f,0.f},{0.f,0.f}};

#pragma unroll 4
    for (int fq = 0; fq < 32; ++fq) {
        float utv[4], uvv[4], a[4][4], bb[2][4];
        *(float4*)utv   = *(const float4*)&us_t[fq*4];
        *(float4*)uvv   = *(const float4*)&us_v[fq*4];
        *(float4*)a[0]  = *(const float4*)&f1s[ti     ][fq*4];
        *(float4*)a[1]  = *(const float4*)&f1s[ti + 16][fq*4];
        *(float4*)a[2]  = *(const float4*)&f1s[ti + 32][fq*4];
        *(float4*)a[3]  = *(const float4*)&f1s[ti + 48][fq*4];
        *(float4*)bb[0] = *(const float4*)&f2s[ni     ][fq*4];
        *(float4*)bb[1] = *(const float4*)&f2s[ni + 16][fq*4];
#pragma unroll
        for (int e = 0; e < 4; ++e) {
#pragma unroll
            for (int m = 0; m < 4; ++m) {
#pragma unroll
                for (int mn = 0; mn < 2; ++mn) {
                    float h = fmaxf(a[m][e] + bb[mn][e], 0.f);
                    at[m][mn] += h * utv[e];
                    av[m][mn] += h * uvv[e];
                }
            }
        }
    }
    float* stz = stp + c * (T*N);
    float* svz = svp + c * (N*T);
#pragma unroll
    for (int m = 0; m < 4; ++m) {
        const int t = t0 + ti + 16*m;
#pragma unroll
        for (int mn = 0; mn < 2; ++mn) {
            const int n = n0 + ni + 16*mn;
            stz[t*N + n] = at[m][mn];
            svz[n*T + t] = av[m][mn];
        }
    }
}

// ---------- node 5: k_att  (combine partials + softmax + context + epilogue) ------
// blocks [0,384)   : out_v tiles (4 t-rows x 128 o-cols; 2 cols/thread)
// blocks [384,576) : out_t tiles (4 n-rows x 128 o-cols; 2 cols/thread)
__global__ __launch_bounds__(256) void k_att(
    const float* __restrict__ stp, const float* __restrict__ svp,
    const float* __restrict__ tg, const float* __restrict__ ve,
    const float* __restrict__ vf, const float* __restrict__ tf,
    float* __restrict__ out_v, float* __restrict__ out_t)
{
    __shared__ float attb[768][4];
    __shared__ float red[4][4];
    __shared__ float ptA[4][4][64];
    __shared__ float ptB[4][4][64];
    const int tid = threadIdx.x;
    const int oo = tid & 63, g = tid >> 6;

    if (blockIdx.x < 384) {
        const int bx = blockIdx.x >> 1, h = blockIdx.x & 1;
        const int t0 = bx * 4;
        const int oA = h*128 + oo, oB = oA + 64;

        float v1[4], v2[4];
#pragma unroll
        for (int r = 0; r < 4; ++r) {
            const float* p = stp + (t0 + r)*N + tid;
            v1[r] = p[0] + p[T*N] + p[2*T*N] + p[3*T*N];
            if (tid < 128) {
                const float* p2 = p + 256;
                v2[r] = p2[0] + p2[T*N] + p2[2*T*N] + p2[3*T*N];
            } else v2[r] = -1e30f;
        }
        float m[4], si[4];
#pragma unroll
        for (int r = 0; r < 4; ++r) {
            float mm = fmaxf(v1[r], v2[r]);
#pragma unroll
            for (int off = 1; off < 64; off <<= 1) mm = fmaxf(mm, __shfl_xor(mm, off));
            if (oo == 0) red[g][r] = mm;
        }
        __syncthreads();
#pragma unroll
        for (int r = 0; r < 4; ++r)
            m[r] = fmaxf(fmaxf(red[0][r], red[1][r]), fmaxf(red[2][r], red[3][r]));
        __syncthreads();
        float e1[4], e2[4];
#pragma unroll
        for (int r = 0; r < 4; ++r) {
            e1[r] = expf(v1[r] - m[r]);
            e2[r] = (tid < 128) ? expf(v2[r] - m[r]) : 0.f;
            float ss = e1[r] + e2[r];
#pragma unroll
            for (int off = 1; off < 64; off <<= 1) ss += __shfl_xor(ss, off);
            if (oo == 0) red[g][r] = ss;
        }
        __syncthreads();
#pragma unroll
        for (int r = 0; r < 4; ++r)
            si[r] = 1.0f / (red[0][r] + red[1][r] + red[2][r] + red[3][r]);
#pragma unroll
        for (int r = 0; r < 4; ++r) {
            attb[tid][r] = e1[r] * si[r];
            if (tid < 128) attb[tid + 256][r] = e2[r] * si[r];
        }
        __syncthreads();

        float accA[4] = {0.f,0.f,0.f,0.f};
        float accB[4] = {0.f,0.f,0.f,0.f};
#pragma unroll 4
        for (int n = g; n < N; n += 4) {
            float4 a0 = *(const float4*)&attb[n][0];
            float tvA = tg[n*D + oA], tvB = tg[n*D + oB];
            accA[0] += a0.x*tvA; accA[1] += a0.y*tvA; accA[2] += a0.z*tvA; accA[3] += a0.w*tvA;
            accB[0] += a0.x*tvB; accB[1] += a0.y*tvB; accB[2] += a0.z*tvB; accB[3] += a0.w*tvB;
        }
#pragma unroll
        for (int r = 0; r < 4; ++r) { ptA[g][r][oo] = accA[r]; ptB[g][r][oo] = accB[r]; }
        __syncthreads();
        if (g < 4) {
            const int rr = g;
            float sA = ptA[0][rr][oo] + ptA[1][rr][oo] + ptA[2][rr][oo] + ptA[3][rr][oo];
            float sB = ptB[0][rr][oo] + ptB[1][rr][oo] + ptB[2][rr][oo] + ptB[3][rr][oo];
            int t = t0 + rr;
            out_v[t*D + oA] = 0.5f*sA + 0.5f*ve[t*D + oA] + vf[t*D + oA];
            out_v[t*D + oB] = 0.5f*sB + 0.5f*ve[t*D + oB] + vf[t*D + oB];
        }
    } else {
        const int b2 = blockIdx.x - 384;
        const int bx = b2 >> 1, h = b2 & 1;
        const int n0 = bx * 4;
        const int oA = h*128 + oo, oB = oA + 64;

        float v1[4], v2[4], v3[4];
#pragma unroll
        for (int r = 0; r < 4; ++r) {
            const float* p = svp + (n0 + r)*T + tid;
            v1[r] = p[0]   + p[N*T]       + p[2*N*T]       + p[3*N*T];
            v2[r] = p[256] + p[N*T + 256] + p[2*N*T + 256] + p[3*N*T + 256];
            v3[r] = p[512] + p[N*T + 512] + p[2*N*T + 512] + p[3*N*T + 512];
        }
        float m[4], si[4];
#pragma unroll
        for (int r = 0; r < 4; ++r) {
            float mm = fmaxf(fmaxf(v1[r], v2[r]), v3[r]);
#pragma unroll
            for (int off = 1; off < 64; off <<= 1) mm = fmaxf(mm, __shfl_xor(mm, off));
            if (oo == 0) red[g][r] = mm;
        }
        __syncthreads();
#pragma unroll
        for (int r = 0; r < 4; ++r)
            m[r] = fmaxf(fmaxf(red[0][r], red[1][r]), fmaxf(red[2][r], red[3][r]));
        __syncthreads();
        float e1[4], e2[4], e3[4];
#pragma unroll
        for (int r = 0; r < 4; ++r) {
            e1[r] = expf(v1[r] - m[r]);
            e2[r] = expf(v2[r] - m[r]);
            e3[r] = expf(v3[r] - m[r]);
            float ss = e1[r] + e2[r] + e3[r];
#pragma unroll
            for (int off = 1; off < 64; off <<= 1) ss += __shfl_xor(ss, off);
            if (oo == 0) red[g][r] = ss;
        }
        __syncthreads();
#pragma unroll
        for (int r = 0; r < 4; ++r)
            si[r] = 1.0f / (red[0][r] + red[1][r] + red[2][r] + red[3][r]);
#pragma unroll
        for (int r = 0; r < 4; ++r) {
            attb[tid][r]       = e1[r] * si[r];
            attb[tid + 256][r] = e2[r] * si[r];
            attb[tid + 512][r] = e3[r] * si[r];
        }
        __syncthreads();

        float accA[4] = {0.f,0.f,0.f,0.f};
        float accB[4] = {0.f,0.f,0.f,0.f};
#pragma unroll 4
        for (int t = g; t < T; t += 4) {
            float4 a0 = *(const float4*)&attb[t][0];
            float vvA = ve[t*D + oA], vvB = ve[t*D + oB];
            accA[0] += a0.x*vvA; accA[1] += a0.y*vvA; accA[2] += a0.z*vvA; accA[3] += a0.w*vvA;
            accB[0] += a0.x*vvB; accB[1] += a0.y*vvB; accB[2] += a0.z*vvB; accB[3] += a0.w*vvB;
        }
#pragma unroll
        for (int r = 0; r < 4; ++r) { ptA[g][r][oo] = accA[r]; ptB[g][r][oo] = accB[r]; }
        __syncthreads();
        if (g < 4) {
            const int rr = g;
            float sA = ptA[0][rr][oo] + ptA[1][rr][oo] + ptA[2][rr][oo] + ptA[3][rr][oo];
            float sB = ptB[0][rr][oo] + ptB[1][rr][oo] + ptB[2][rr][oo] + ptB[3][rr][oo];
            int n = n0 + rr;
            out_t[n*D + oA] = 0.5f*sA + 0.5f*tg[n*D + oA] + tf[n*D + oA];
            out_t[n*D + oB] = 0.5f*sB + 0.5f*tg[n*D + oB] + tf[n*D + oB];
        }
    }
}

extern "C" void kernel_launch(void* const* d_in, const int* in_sizes, int n_in,
                              void* d_out, int out_size, void* d_ws, size_t ws_size,
                              hipStream_t stream)
{
    (void)in_sizes; (void)n_in; (void)out_size; (void)ws_size;
    const float* vf   = (const float*)d_in[0];
    const float* tf   = (const float*)d_in[1];
    const float* vpos = (const float*)d_in[2];
    const float* tpos = (const float*)d_in[3];
    const float* cw   = (const float*)d_in[4];
    const float* cb   = (const float*)d_in[5];
    const float* bil  = (const float*)d_in[6];
    const float* lw   = (const float*)d_in[7];
    const float* lb   = (const float*)d_in[8];
    const float* W1   = (const float*)d_in[9];
    const float* b1   = (const float*)d_in[10];
    const float* W2   = (const float*)d_in[11];
    const float* Wi   = (const float*)d_in[12];
    // d_in[13]=bi, d_in[15]=bt, d_in[17]=bv: softmax-invariant constant shifts -> unused
    const float* wt   = (const float*)d_in[14];
    const float* wv   = (const float*)d_in[16];

    float* ws  = (float*)d_ws;
    float* ve  = ws;                // T*D
    float* tn  = ve + T*D;          // N*D
    float* tg  = tn + N*D;          // N*D
    float* tl  = tg + N*D;          // N*D
    float* f1  = tl + N*D;          // T*FD
    float* f2  = f1 + T*FD;         // N*FD
    float* q   = f2 + N*FD;         // D
    float* ut  = q + D;             // FD
    float* uv  = ut + FD;           // FD
    float* stp = uv + FD;           // 4*T*N
    float* svp = stp + 4*T*N;       // 4*N*T

    float* out_v = (float*)d_out;
    float* out_t = out_v + T*D;

    hipLaunchKernelGGL(k_front, dim3(292),       dim3(256), 0, stream,
                       vf, vpos, cw, cb, tf, tpos, Wi, wt, wv, ve, tn, ut, uv);
    hipLaunchKernelGGL(k_mid,   dim3(488),       dim3(256), 0, stream,
                       ve, W1, b1, tn, bil, lw, lb, f1, q, tl);
    hipLaunchKernelGGL(k_f2,    dim3(192),       dim3(256), 0, stream, tn, q, tl, W2, tg, f2);
    hipLaunchKernelGGL(k_score, dim3(12, 12, 4), dim3(256), 0, stream, f1, f2, ut, uv, stp, svp);
    hipLaunchKernelGGL(k_att,   dim3(576),       dim3(256), 0, stream, stp, svp, tg, ve, vf, tf, out_v, out_t);
}

// Round 8
// 99.219 us; speedup vs baseline: 1.4243x; 1.0321x over previous
//
#include <hip/hip_runtime.h>
#include <math.h>

#define D  256
#define T  768
#define N  384
#define FD 512

#define DOT4(A,B) ((A).x*(B).x + (A).y*(B).y + (A).z*(B).z + (A).w*(B).w)

// ---------- node 1: k_front ------------------------------------------------------
// blocks [0,288)   : conv partial GEMM, k fixed per z: vep[k] = vpe(shift k-1) @ cw[:,:,k].T
//                    tile 64t x 32o, micro 4x2, K=256 in 4 chunks  (no bias/relu yet)
// blocks [288,384) : text row-l2-normalize -> tn
// blocks [384,480) : tl = tn @ lin_w.T + lin_b  (norm folded as row-scale)
// blocks [480,484) : ut/uv = Wi.T @ wt/wv
__global__ __launch_bounds__(256) void k_front(
    const float* __restrict__ vf, const float* __restrict__ vpos,
    const float* __restrict__ cw,
    const float* __restrict__ tf, const float* __restrict__ tpos,
    const float* __restrict__ lin_w, const float* __restrict__ lin_b,
    const float* __restrict__ Wi, const float* __restrict__ wt,
    const float* __restrict__ wv,
    float* __restrict__ vep, float* __restrict__ tn,
    float* __restrict__ tl, float* __restrict__ ut, float* __restrict__ uv)
{
    __shared__ float smem[10880];
    const int b = blockIdx.x, tid = threadIdx.x;

    if (b < 288) {
        // conv partial: decode (io, it, k)
        const int k  = b % 3;
        const int rem = b / 3;
        const int t0 = (rem % 12) * 64;
        const int o0 = (rem / 12) * 32;
        float (*As)[68] = (float(*)[68])smem;            // 64 x 68
        float (*Bs)[68] = (float(*)[68])(smem + 4352);   // 32 x 68
        const int p = tid >> 4, oi = tid & 15;
        float a00=0.f,a01=0.f,a10=0.f,a11=0.f,a20=0.f,a21=0.f,a30=0.f,a31=0.f;

        for (int c = 0; c < 4; ++c) {
            const int i0 = c << 6;
            __syncthreads();
#pragma unroll
            for (int s = 0; s < 4; ++s) {
                int u = tid + (s << 8);
                int r = u >> 4, q4 = (u & 15) * 4;
                int gr = t0 + r + k - 1;
                float4 v = make_float4(0.f,0.f,0.f,0.f);
                if (gr >= 0 && gr < T) {
                    float4 x = *(const float4*)&vf[gr*D + i0 + q4];
                    float4 y = *(const float4*)&vpos[gr*D + i0 + q4];
                    v = make_float4(x.x+y.x, x.y+y.y, x.z+y.z, x.w+y.w);
                }
                *(float4*)&As[r][q4] = v;
            }
#pragma unroll
            for (int s = 0; s < 8; ++s) {
                int u = tid + (s << 8);
                int o = u >> 6, i = u & 63;
                Bs[o][i] = cw[(o0 + o)*768 + (i0 + i)*3 + k];
            }
            __syncthreads();
#pragma unroll 4
            for (int kc4 = 0; kc4 < 16; ++kc4) {
                float4 r0 = *(const float4*)&As[4*p    ][kc4*4];
                float4 r1 = *(const float4*)&As[4*p + 1][kc4*4];
                float4 r2 = *(const float4*)&As[4*p + 2][kc4*4];
                float4 r3 = *(const float4*)&As[4*p + 3][kc4*4];
                float4 b0 = *(const float4*)&Bs[oi     ][kc4*4];
                float4 b1 = *(const float4*)&Bs[oi + 16][kc4*4];
                a00 += DOT4(r0,b0); a01 += DOT4(r0,b1);
                a10 += DOT4(r1,b0); a11 += DOT4(r1,b1);
                a20 += DOT4(r2,b0); a21 += DOT4(r2,b1);
                a30 += DOT4(r3,b0); a31 += DOT4(r3,b1);
            }
        }
        float* vz = vep + k * (T*D);
        const int t = t0 + 4*p;
        vz[(t  )*D + o0 + oi] = a00;  vz[(t  )*D + o0 + oi + 16] = a01;
        vz[(t+1)*D + o0 + oi] = a10;  vz[(t+1)*D + o0 + oi + 16] = a11;
        vz[(t+2)*D + o0 + oi] = a20;  vz[(t+2)*D + o0 + oi + 16] = a21;
        vz[(t+3)*D + o0 + oi] = a30;  vz[(t+3)*D + o0 + oi + 16] = a31;
    } else if (b < 384) {
        const int wid = tid >> 6, lane = tid & 63;
        const int r = (b - 288)*4 + wid;
        float v[4]; float ss = 0.f;
#pragma unroll
        for (int kk = 0; kk < 4; ++kk) {
            v[kk] = tf[r*D + lane + 64*kk] + tpos[r*D + lane + 64*kk];
            ss += v[kk]*v[kk];
        }
#pragma unroll
        for (int off = 1; off < 64; off <<= 1) ss += __shfl_xor(ss, off);
        float inv = 1.0f / fmaxf(sqrtf(ss), 1e-12f);
#pragma unroll
        for (int kk = 0; kk < 4; ++kk) tn[r*D + lane + 64*kk] = v[kk] * inv;
    } else if (b < 480) {
        // tl tile 32n x 32o; raw A resident, norm folded at write
        const int bb = b - 384;
        const int n0 = (bb >> 3) * 32;
        const int o0 = (bb & 7) * 32;
        float (*As2)[260] = (float(*)[260])smem;          // 32 x 260
        float (*Bs2)[68]  = (float(*)[68])(smem + 8320);  // 32 x 68
        float* inv = smem + 10496;                        // 32
#pragma unroll
        for (int s = 0; s < 8; ++s) {
            int u = tid + (s << 8);
            int r = u >> 6, q4 = (u & 63) * 4;
            float4 x = *(const float4*)&tf[(n0 + r)*D + q4];
            float4 y = *(const float4*)&tpos[(n0 + r)*D + q4];
            *(float4*)&As2[r][q4] = make_float4(x.x+y.x, x.y+y.y, x.z+y.z, x.w+y.w);
        }
        __syncthreads();
        {
            const int r = tid >> 3, j = tid & 7;
            float p = 0.f;
#pragma unroll
            for (int m = 0; m < 8; ++m) {
                float4 a = *(const float4*)&As2[r][j*32 + m*4];
                p += DOT4(a, a);
            }
            p += __shfl_xor(p, 1); p += __shfl_xor(p, 2); p += __shfl_xor(p, 4);
            if (j == 0) inv[r] = 1.0f / fmaxf(sqrtf(p), 1e-12f);
        }
        const int tA = tid >> 4, oA = tid & 15;
        float acc00=0.f, acc01=0.f, acc10=0.f, acc11=0.f;
        for (int c = 0; c < 4; ++c) {
            const int d0 = c << 6;
            __syncthreads();
#pragma unroll
            for (int s = 0; s < 2; ++s) {
                int u = tid + (s << 8);
                int o = u >> 4, q4 = (u & 15) * 4;
                *(float4*)&Bs2[o][q4] = *(const float4*)&lin_w[(o0 + o)*D + d0 + q4];
            }
            __syncthreads();
#pragma unroll 4
            for (int kc4 = 0; kc4 < 16; ++kc4) {
                float4 a0 = *(const float4*)&As2[tA     ][d0 + kc4*4];
                float4 a1 = *(const float4*)&As2[tA + 16][d0 + kc4*4];
                float4 b0 = *(const float4*)&Bs2[oA     ][kc4*4];
                float4 b1 = *(const float4*)&Bs2[oA + 16][kc4*4];
                acc00 += DOT4(a0,b0); acc01 += DOT4(a0,b1);
                acc10 += DOT4(a1,b0); acc11 += DOT4(a1,b1);
            }
        }
        const float i0n = inv[tA], i1n = inv[tA + 16];
        const float lb0 = lin_b[o0 + oA], lb1 = lin_b[o0 + oA + 16];
        tl[(n0 + tA     )*D + o0 + oA]      = i0n*acc00 + lb0;
        tl[(n0 + tA     )*D + o0 + oA + 16] = i0n*acc01 + lb1;
        tl[(n0 + tA + 16)*D + o0 + oA]      = i1n*acc10 + lb0;
        tl[(n0 + tA + 16)*D + o0 + oA + 16] = i1n*acc11 + lb1;
    } else {
        float* wsm = smem;
        const int which = b - 480;                  // 0,1 -> ut ; 2,3 -> uv
        const float* w = (which < 2) ? wt : wv;
        float* u = (which < 2) ? ut : uv;
        const int f = ((which & 1) << 8) + tid;
        wsm[tid] = w[tid];
        __syncthreads();
        float s = 0.f;
#pragma unroll 4
        for (int d = 0; d < D; ++d) s += wsm[d] * Wi[d*FD + f];
        u[f] = s;
    }
}

// ---------- node 2: k_mid --------------------------------------------------------
// blocks [0,192)   : f1 = relu(sum vep + cb) @ W1.T + b1  (64t x 32f, 4x2 micro)
// blocks [192,288) : f2raw = tl @ W2.T                    (64n x 32f, 4x2 micro)
// blocks [288,384) : ve = relu(sum vep + cb)  materialize (8 rows/block)
// blocks [384,392) : q = (mean_rows tn) @ bil_w
__global__ __launch_bounds__(256) void k_mid(
    const float* __restrict__ vep, const float* __restrict__ cbp,
    const float* __restrict__ W1, const float* __restrict__ b1v,
    const float* __restrict__ tlp, const float* __restrict__ W2,
    const float* __restrict__ tn, const float* __restrict__ bil,
    float* __restrict__ f1, float* __restrict__ f2,
    float* __restrict__ ve, float* __restrict__ q)
{
    __shared__ float smem[6656];
    const int b = blockIdx.x, tid = threadIdx.x;

    if (b < 288) {
        const bool isF1 = (b < 192);
        const int bb = isF1 ? b : b - 192;
        const int nT = isF1 ? 12 : 6;
        const int r0 = (bb % nT) * 64;            // t0 or n0
        const int f0 = (bb / nT) * 32;
        float (*As)[68] = (float(*)[68])smem;            // 64 x 68
        float (*Bs)[68] = (float(*)[68])(smem + 4352);   // 32 x 68
        const int p = tid >> 4, fi = tid & 15;
        float a00=0.f,a01=0.f,a10=0.f,a11=0.f,a20=0.f,a21=0.f,a30=0.f,a31=0.f;
        const float* Wp = isF1 ? W1 : W2;

        for (int c = 0; c < 4; ++c) {
            const int d0 = c << 6;
            __syncthreads();
            if (isF1) {
#pragma unroll
                for (int s = 0; s < 4; ++s) {
                    int u = tid + (s << 8);
                    int r = u >> 4, q4 = (u & 15) * 4;
                    const int off = (r0 + r)*D + d0 + q4;
                    float4 p0 = *(const float4*)&vep[off];
                    float4 p1 = *(const float4*)&vep[T*D + off];
                    float4 p2 = *(const float4*)&vep[2*T*D + off];
                    float4 cbv = *(const float4*)&cbp[d0 + q4];
                    float4 v;
                    v.x = fmaxf(p0.x+p1.x+p2.x+cbv.x, 0.f);
                    v.y = fmaxf(p0.y+p1.y+p2.y+cbv.y, 0.f);
                    v.z = fmaxf(p0.z+p1.z+p2.z+cbv.z, 0.f);
                    v.w = fmaxf(p0.w+p1.w+p2.w+cbv.w, 0.f);
                    *(float4*)&As[r][q4] = v;
                }
            } else {
#pragma unroll
                for (int s = 0; s < 4; ++s) {
                    int u = tid + (s << 8);
                    int r = u >> 4, q4 = (u & 15) * 4;
                    *(float4*)&As[r][q4] = *(const float4*)&tlp[(r0 + r)*D + d0 + q4];
                }
            }
#pragma unroll
            for (int s = 0; s < 2; ++s) {
                int u = tid + (s << 8);
                int o = u >> 4, q4 = (u & 15) * 4;
                *(float4*)&Bs[o][q4] = *(const float4*)&Wp[(f0 + o)*D + d0 + q4];
            }
            __syncthreads();
#pragma unroll 4
            for (int kc4 = 0; kc4 < 16; ++kc4) {
                float4 r0v = *(const float4*)&As[4*p    ][kc4*4];
                float4 r1v = *(const float4*)&As[4*p + 1][kc4*4];
                float4 r2v = *(const float4*)&As[4*p + 2][kc4*4];
                float4 r3v = *(const float4*)&As[4*p + 3][kc4*4];
                float4 b0 = *(const float4*)&Bs[fi     ][kc4*4];
                float4 b1 = *(const float4*)&Bs[fi + 16][kc4*4];
                a00 += DOT4(r0v,b0); a01 += DOT4(r0v,b1);
                a10 += DOT4(r1v,b0); a11 += DOT4(r1v,b1);
                a20 += DOT4(r2v,b0); a21 += DOT4(r2v,b1);
                a30 += DOT4(r3v,b0); a31 += DOT4(r3v,b1);
            }
        }
        const int r = r0 + 4*p;
        if (isF1) {
            const float bi0 = b1v[f0 + fi], bi1 = b1v[f0 + fi + 16];
            f1[(r  )*FD + f0 + fi] = a00 + bi0;  f1[(r  )*FD + f0 + fi + 16] = a01 + bi1;
            f1[(r+1)*FD + f0 + fi] = a10 + bi0;  f1[(r+1)*FD + f0 + fi + 16] = a11 + bi1;
            f1[(r+2)*FD + f0 + fi] = a20 + bi0;  f1[(r+2)*FD + f0 + fi + 16] = a21 + bi1;
            f1[(r+3)*FD + f0 + fi] = a30 + bi0;  f1[(r+3)*FD + f0 + fi + 16] = a31 + bi1;
        } else {
            f2[(r  )*FD + f0 + fi] = a00;  f2[(r  )*FD + f0 + fi + 16] = a01;
            f2[(r+1)*FD + f0 + fi] = a10;  f2[(r+1)*FD + f0 + fi + 16] = a11;
            f2[(r+2)*FD + f0 + fi] = a20;  f2[(r+2)*FD + f0 + fi + 16] = a21;
            f2[(r+3)*FD + f0 + fi] = a30;  f2[(r+3)*FD + f0 + fi + 16] = a31;
        }
    } else if (b < 384) {
        const int t0 = (b - 288) * 8;
        float cbv = cbp[tid];
#pragma unroll
        for (int r = 0; r < 8; ++r) {
            const int off = (t0 + r)*D + tid;
            float s = vep[off] + vep[T*D + off] + vep[2*T*D + off] + cbv;
            ve[off] = fmaxf(s, 0.f);
        }
    } else {
        float* tb = smem;                              // 256
        float (*qp)[32] = (float(*)[32])(smem + 256);  // 8 x 32
        const int bq = b - 384;
        float s = 0.f;
#pragma unroll 8
        for (int n = 0; n < N; ++n) s += tn[n*D + tid];
        tb[tid] = s * (1.0f / (float)N);
        __syncthreads();
        const int o = tid & 31, dg = tid >> 5;
        float p = 0.f;
#pragma unroll 8
        for (int d = dg*32; d < dg*32 + 32; ++d) p += tb[d] * bil[d*D + bq*32 + o];
        qp[dg][o] = p;
        __syncthreads();
        if (tid < 32) {
            float acc = 0.f;
#pragma unroll
            for (int kk = 0; kk < 8; ++kk) acc += qp[kk][tid];
            q[bq*32 + tid] = acc;
        }
    }
}

// ---------- node 3: k_score ------------------------------------------------------
// blocks [0,576)   : 64t x 64n tile, 4x4 micro, FD split z=8 (K-slice 64),
//                    gate w=sigmoid(tn.q) recomputed inline, applied at f2 staging
// blocks [576,588) : tg = w * tl  (32 rows/block)
__global__ __launch_bounds__(256) void k_score(
    const float* __restrict__ f1, const float* __restrict__ f2,
    const float* __restrict__ tn, const float* __restrict__ qv,
    const float* __restrict__ tlp,
    const float* __restrict__ ut, const float* __restrict__ uv,
    float* __restrict__ stp, float* __restrict__ svp, float* __restrict__ tg)
{
    __shared__ float smem[9216];
    const int tid = threadIdx.x;
    const int bid = blockIdx.x;

    if (bid < 576) {
        const int t0 = (bid % 12) * 64;
        const int n0 = ((bid / 12) % 6) * 64;
        const int iz = bid / 72;
        const int fz = iz * 64;
        float (*f1s)[68] = (float(*)[68])smem;            // 64 x 68
        float (*f2s)[68] = (float(*)[68])(smem + 4352);   // 64 x 68
        float* qs   = smem + 8704;   // 256
        float* us_t = smem + 8960;   // 64
        float* us_v = smem + 9024;   // 64
        float* wsm  = smem + 9088;   // 64

        qs[tid] = qv[tid];
        if (tid < 64) us_t[tid] = ut[fz + tid];
        else if (tid < 128) us_v[tid - 64] = uv[fz + tid - 64];
        __syncthreads();
        {   // w for 64 n-rows: 4 lanes per row
            const int r = tid >> 2, j = tid & 3;
            float p = 0.f;
#pragma unroll
            for (int m = 0; m < 16; ++m) {
                float4 a = *(const float4*)&tn[(n0 + r)*D + j*64 + m*4];
                float4 qq = *(const float4*)&qs[j*64 + m*4];
                p += DOT4(a, qq);
            }
            p += __shfl_xor(p, 1); p += __shfl_xor(p, 2);
            if (j == 0) wsm[r] = 1.0f / (1.0f + expf(-p));
        }
        // stage f1s (independent of wsm)
#pragma unroll
        for (int s = 0; s < 4; ++s) {
            int u = tid + (s << 8);
            int r = u >> 4, q4 = (u & 15) * 4;
            *(float4*)&f1s[r][q4] = *(const float4*)&f1[(t0 + r)*FD + fz + q4];
        }
        __syncthreads();
        // stage f2s scaled by gate
#pragma unroll
        for (int s = 0; s < 4; ++s) {
            int u = tid + (s << 8);
            int r = u >> 4, q4 = (u & 15) * 4;
            float w = wsm[r];
            float4 v = *(const float4*)&f2[(n0 + r)*FD + fz + q4];
            *(float4*)&f2s[r][q4] = make_float4(w*v.x, w*v.y, w*v.z, w*v.w);
        }
        __syncthreads();

        const int ti = tid >> 4, ni = tid & 15;
        float at[4][4], av[4][4];
#pragma unroll
        for (int i = 0; i < 4; ++i)
#pragma unroll
            for (int j = 0; j < 4; ++j) { at[i][j] = 0.f; av[i][j] = 0.f; }

#pragma unroll 2
        for (int fq = 0; fq < 16; ++fq) {
            float a[4][4], bb[4][4], utv[4], uvv[4];
            *(float4*)utv  = *(const float4*)&us_t[fq*4];
            *(float4*)uvv  = *(const float4*)&us_v[fq*4];
#pragma unroll
            for (int i = 0; i < 4; ++i) {
                *(float4*)a[i]  = *(const float4*)&f1s[ti + 16*i][fq*4];
                *(float4*)bb[i] = *(const float4*)&f2s[ni + 16*i][fq*4];
            }
#pragma unroll
            for (int e = 0; e < 4; ++e) {
#pragma unroll
                for (int i = 0; i < 4; ++i) {
#pragma unroll
                    for (int j = 0; j < 4; ++j) {
                        float h = fmaxf(a[i][e] + bb[j][e], 0.f);
                        at[i][j] += h * utv[e];
                        av[i][j] += h * uvv[e];
                    }
                }
            }
        }
        float* stz = stp + iz * (T*N);
        float* svz = svp + iz * (N*T);
#pragma unroll
        for (int i = 0; i < 4; ++i) {
            const int t = t0 + ti + 16*i;
#pragma unroll
            for (int j = 0; j < 4; ++j) {
                const int n = n0 + ni + 16*j;
                stz[t*N + n] = at[i][j];
                svz[n*T + t] = av[i][j];
            }
        }
    } else {
        // tg = w * tl for 32 rows
        const int n0 = (bid - 576) * 32;
        float* qs  = smem;        // 256
        float* wsm = smem + 256;  // 32
        qs[tid] = qv[tid];
        __syncthreads();
        {
            const int r = tid >> 3, j = tid & 7;
            float p = 0.f;
#pragma unroll
            for (int m = 0; m < 8; ++m) {
                float4 a = *(const float4*)&tn[(n0 + r)*D + j*32 + m*4];
                float4 qq = *(const float4*)&qs[j*32 + m*4];
                p += DOT4(a, qq);
            }
            p += __shfl_xor(p, 1); p += __shfl_xor(p, 2); p += __shfl_xor(p, 4);
            if (j == 0) wsm[r] = 1.0f / (1.0f + expf(-p));
        }
        __syncthreads();
#pragma unroll
        for (int r = 0; r < 32; ++r)
            tg[(n0 + r)*D + tid] = wsm[r] * tlp[(n0 + r)*D + tid];
    }
}

// ---------- node 4: k_att  (combine 8 partials + softmax + context + epilogue) ----
// blocks [0,384)   : out_v tiles (4 t-rows x 128 o-cols; 2 cols/thread)
// blocks [384,576) : out_t tiles (4 n-rows x 128 o-cols; 2 cols/thread)
__global__ __launch_bounds__(256) void k_att(
    const float* __restrict__ stp, const float* __restrict__ svp,
    const float* __restrict__ tg, const float* __restrict__ ve,
    const float* __restrict__ vf, const float* __restrict__ tf,
    float* __restrict__ out_v, float* __restrict__ out_t)
{
    __shared__ float attb[768][4];
    __shared__ float red[4][4];
    __shared__ float ptA[4][4][64];
    __shared__ float ptB[4][4][64];
    const int tid = threadIdx.x;
    const int oo = tid & 63, g = tid >> 6;
    const int TN = T*N;

    if (blockIdx.x < 384) {
        const int bx = blockIdx.x >> 1, h = blockIdx.x & 1;
        const int t0 = bx * 4;
        const int oA = h*128 + oo, oB = oA + 64;

        float v1[4], v2[4];
#pragma unroll
        for (int r = 0; r < 4; ++r) {
            const float* p = stp + (t0 + r)*N + tid;
            float s1 = 0.f;
#pragma unroll
            for (int z = 0; z < 8; ++z) s1 += p[z*TN];
            v1[r] = s1;
            if (tid < 128) {
                float s2 = 0.f;
#pragma unroll
                for (int z = 0; z < 8; ++z) s2 += p[z*TN + 256];
                v2[r] = s2;
            } else v2[r] = -1e30f;
        }
        float m[4], si[4];
#pragma unroll
        for (int r = 0; r < 4; ++r) {
            float mm = fmaxf(v1[r], v2[r]);
#pragma unroll
            for (int off = 1; off < 64; off <<= 1) mm = fmaxf(mm, __shfl_xor(mm, off));
            if (oo == 0) red[g][r] = mm;
        }
        __syncthreads();
#pragma unroll
        for (int r = 0; r < 4; ++r)
            m[r] = fmaxf(fmaxf(red[0][r], red[1][r]), fmaxf(red[2][r], red[3][r]));
        __syncthreads();
        float e1[4], e2[4];
#pragma unroll
        for (int r = 0; r < 4; ++r) {
            e1[r] = expf(v1[r] - m[r]);
            e2[r] = (tid < 128) ? expf(v2[r] - m[r]) : 0.f;
            float ss = e1[r] + e2[r];
#pragma unroll
            for (int off = 1; off < 64; off <<= 1) ss += __shfl_xor(ss, off);
            if (oo == 0) red[g][r] = ss;
        }
        __syncthreads();
#pragma unroll
        for (int r = 0; r < 4; ++r)
            si[r] = 1.0f / (red[0][r] + red[1][r] + red[2][r] + red[3][r]);
#pragma unroll
        for (int r = 0; r < 4; ++r) {
            attb[tid][r] = e1[r] * si[r];
            if (tid < 128) attb[tid + 256][r] = e2[r] * si[r];
        }
        __syncthreads();

        float accA[4] = {0.f,0.f,0.f,0.f};
        float accB[4] = {0.f,0.f,0.f,0.f};
#pragma unroll 4
        for (int n = g; n < N; n += 4) {
            float4 a0 = *(const float4*)&attb[n][0];
            float tvA = tg[n*D + oA], tvB = tg[n*D + oB];
            accA[0] += a0.x*tvA; accA[1] += a0.y*tvA; accA[2] += a0.z*tvA; accA[3] += a0.w*tvA;
            accB[0] += a0.x*tvB; accB[1] += a0.y*tvB; accB[2] += a0.z*tvB; accB[3] += a0.w*tvB;
        }
#pragma unroll
        for (int r = 0; r < 4; ++r) { ptA[g][r][oo] = accA[r]; ptB[g][r][oo] = accB[r]; }
        __syncthreads();
        if (g < 4) {
            const int rr = g;
            float sA = ptA[0][rr][oo] + ptA[1][rr][oo] + ptA[2][rr][oo] + ptA[3][rr][oo];
            float sB = ptB[0][rr][oo] + ptB[1][rr][oo] + ptB[2][rr][oo] + ptB[3][rr][oo];
            int t = t0 + rr;
            out_v[t*D + oA] = 0.5f*sA + 0.5f*ve[t*D + oA] + vf[t*D + oA];
            out_v[t*D + oB] = 0.5f*sB + 0.5f*ve[t*D + oB] + vf[t*D + oB];
        }
    } else {
        const int b2 = blockIdx.x - 384;
        const int bx = b2 >> 1, h = b2 & 1;
        const int n0 = bx * 4;
        const int oA = h*128 + oo, oB = oA + 64;

        float v1[4], v2[4], v3[4];
#pragma unroll
        for (int r = 0; r < 4; ++r) {
            const float* p = svp + (n0 + r)*T + tid;
            float s1 = 0.f, s2 = 0.f, s3 = 0.f;
#pragma unroll
            for (int z = 0; z < 8; ++z) {
                s1 += p[z*TN];
                s2 += p[z*TN + 256];
                s3 += p[z*TN + 512];
            }
            v1[r] = s1; v2[r] = s2; v3[r] = s3;
        }
        float m[4], si[4];
#pragma unroll
        for (int r = 0; r < 4; ++r) {
            float mm = fmaxf(fmaxf(v1[r], v2[r]), v3[r]);
#pragma unroll
            for (int off = 1; off < 64; off <<= 1) mm = fmaxf(mm, __shfl_xor(mm, off));
            if (oo == 0) red[g][r] = mm;
        }
        __syncthreads();
#pragma unroll
        for (int r = 0; r < 4; ++r)
            m[r] = fmaxf(fmaxf(red[0][r], red[1][r]), fmaxf(red[2][r], red[3][r]));
        __syncthreads();
        float e1[4], e2[4], e3[4];
#pragma unroll
        for (int r = 0; r < 4; ++r) {
            e1[r] = expf(v1[r] - m[r]);
            e2[r] = expf(v2[r] - m[r]);
            e3[r] = expf(v3[r] - m[r]);
            float ss = e1[r] + e2[r] + e3[r];
#pragma unroll
            for (int off = 1; off < 64; off <<= 1) ss += __shfl_xor(ss, off);
            if (oo == 0) red[g][r] = ss;
        }
        __syncthreads();
#pragma unroll
        for (int r = 0; r < 4; ++r)
            si[r] = 1.0f / (red[0][r] + red[1][r] + red[2][r] + red[3][r]);
#pragma unroll
        for (int r = 0; r < 4; ++r) {
            attb[tid][r]       = e1[r] * si[r];
            attb[tid + 256][r] = e2[r] * si[r];
            attb[tid + 512][r] = e3[r] * si[r];
        }
        __syncthreads();

        float accA[4] = {0.f,0.f,0.f,0.f};
        float accB[4] = {0.f,0.f,0.f,0.f};
#pragma unroll 4
        for (int t = g; t < T; t += 4) {
            float4 a0 = *(const float4*)&attb[t][0];
            float vvA = ve[t*D + oA], vvB = ve[t*D + oB];
            accA[0] += a0.x*vvA; accA[1] += a0.y*vvA; accA[2] += a0.z*vvA; accA[3] += a0.w*vvA;
            accB[0] += a0.x*vvB; accB[1] += a0.y*vvB; accB[2] += a0.z*vvB; accB[3] += a0.w*vvB;
        }
#pragma unroll
        for (int r = 0; r < 4; ++r) { ptA[g][r][oo] = accA[r]; ptB[g][r][oo] = accB[r]; }
        __syncthreads();
        if (g < 4) {
            const int rr = g;
            float sA = ptA[0][rr][oo] + ptA[1][rr][oo] + ptA[2][rr][oo] + ptA[3][rr][oo];
            float sB = ptB[0][rr][oo] + ptB[1][rr][oo] + ptB[2][rr][oo] + ptB[3][rr][oo];
            int n = n0 + rr;
            out_t[n*D + oA] = 0.5f*sA + 0.5f*tg[n*D + oA] + tf[n*D + oA];
            out_t[n*D + oB] = 0.5f*sB + 0.5f*tg[n*D + oB] + tf[n*D + oB];
        }
    }
}

extern "C" void kernel_launch(void* const* d_in, const int* in_sizes, int n_in,
                              void* d_out, int out_size, void* d_ws, size_t ws_size,
                              hipStream_t stream)
{
    (void)in_sizes; (void)n_in; (void)out_size; (void)ws_size;
    const float* vf   = (const float*)d_in[0];
    const float* tf   = (const float*)d_in[1];
    const float* vpos = (const float*)d_in[2];
    const float* tpos = (const float*)d_in[3];
    const float* cw   = (const float*)d_in[4];
    const float* cb   = (const float*)d_in[5];
    const float* bil  = (const float*)d_in[6];
    const float* lw   = (const float*)d_in[7];
    const float* lb   = (const float*)d_in[8];
    const float* W1   = (const float*)d_in[9];
    const float* b1   = (const float*)d_in[10];
    const float* W2   = (const float*)d_in[11];
    const float* Wi   = (const float*)d_in[12];
    // d_in[13]=bi, d_in[15]=bt, d_in[17]=bv: softmax-invariant constant shifts -> unused
    const float* wt   = (const float*)d_in[14];
    const float* wv   = (const float*)d_in[16];

    float* ws  = (float*)d_ws;
    float* vep = ws;                // 3*T*D
    float* ve  = vep + 3*T*D;       // T*D
    float* tn  = ve + T*D;          // N*D
    float* tl  = tn + N*D;          // N*D
    float* tg  = tl + N*D;          // N*D
    float* f1  = tg + N*D;          // T*FD
    float* f2  = f1 + T*FD;         // N*FD
    float* q   = f2 + N*FD;         // D
    float* ut  = q + D;             // FD
    float* uv  = ut + FD;           // FD
    float* stp = uv + FD;           // 8*T*N
    float* svp = stp + 8*T*N;       // 8*N*T

    float* out_v = (float*)d_out;
    float* out_t = out_v + T*D;

    hipLaunchKernelGGL(k_front, dim3(484), dim3(256), 0, stream,
                       vf, vpos, cw, tf, tpos, lw, lb, Wi, wt, wv, vep, tn, tl, ut, uv);
    hipLaunchKernelGGL(k_mid,   dim3(392), dim3(256), 0, stream,
                       vep, cb, W1, b1, tl, W2, tn, bil, f1, f2, ve, q);
    hipLaunchKernelGGL(k_score, dim3(588), dim3(256), 0, stream,
                       f1, f2, tn, q, tl, ut, uv, stp, svp, tg);
    hipLaunchKernelGGL(k_att,   dim3(576), dim3(256), 0, stream,
                       stp, svp, tg, ve, vf, tf, out_v, out_t);
}